// Round 2
// baseline (316.385 us; speedup 1.0000x reference)
//
#include <hip/hip_runtime.h>

// (B,T,C)=(2,2048,1024), NH=16, NKV=4, HD=64, VEC=32
typedef __bf16 bf16x8 __attribute__((ext_vector_type(8)));
typedef float f32x4 __attribute__((ext_vector_type(4)));

__device__ inline float tof(float v) { return v; }
__device__ inline float tof(__bf16 v) { return (float)v; }

__device__ inline bf16x8 load8(const __bf16* p) { return *(const bf16x8*)p; }
__device__ inline bf16x8 load8(const float* p) {
    const float4 a = *(const float4*)p;
    const float4 b = *(const float4*)(p + 4);
    bf16x8 r;
    r[0] = (__bf16)a.x; r[1] = (__bf16)a.y; r[2] = (__bf16)a.z; r[3] = (__bf16)a.w;
    r[4] = (__bf16)b.x; r[5] = (__bf16)b.y; r[6] = (__bf16)b.z; r[7] = (__bf16)b.w;
    return r;
}

// ---------------------------------------------------------------------------
// Kernel 0: dtype sniffer. Reads first 512 uint16 of x; if interpreted-as-bf16
// values have many wild exponents, x is float32 (flag=1), else bf16 (flag=0).
// ---------------------------------------------------------------------------
__global__ void sniff_kernel(const unsigned short* __restrict__ xs, int* flag) {
    if (threadIdx.x != 0) return;
    int bad = 0;
    for (int i = 0; i < 512; ++i) {
        unsigned int f = ((unsigned int)xs[i]) << 16;
        float v = __uint_as_float(f);
        float a = fabsf(v);
        if (!(a <= 1e4f) || (a != 0.f && a < 1e-6f)) bad++;  // NaN fails a<=1e4
    }
    *flag = (bad > 32) ? 1 : 0;
}

// ---------------------------------------------------------------------------
// Kernel 1: fused QKV projection + gate*ve + RoPE + RMSNorm
// Grid: (4096/64, 24). cb<16: q head; cb<20: k head; else v head
// ---------------------------------------------------------------------------
template <typename T>
__global__ __launch_bounds__(256) void qkv_kernel(
    const T* __restrict__ x, const T* __restrict__ ve,
    const T* __restrict__ cosp, const T* __restrict__ sinp,
    const T* __restrict__ Wq, const T* __restrict__ Wk,
    const T* __restrict__ Wv, const T* __restrict__ Wgate,
    __bf16* __restrict__ qo, __bf16* __restrict__ ko, __bf16* __restrict__ vo,
    const int* __restrict__ flag)
{
    if (*flag != (int)(sizeof(T) == 4)) return;

    const int row0 = blockIdx.x * 64;
    const int cb = blockIdx.y;
    const T* Wp; int ldw, col0, h, mode;
    if (cb < 16)      { Wp = Wq; ldw = 1024; col0 = cb * 64;        h = cb;      mode = 0; }
    else if (cb < 20) { Wp = Wk; ldw = 256;  col0 = (cb - 16) * 64; h = cb - 16; mode = 1; }
    else              { Wp = Wv; ldw = 256;  col0 = (cb - 20) * 64; h = cb - 20; mode = 2; }

    __shared__ __bf16 As[64 * 40];   // [row][k]
    __shared__ __bf16 Bs[64 * 40];   // [col][k] (transposed)
    __shared__ float  gateS[64];

    const int tid  = threadIdx.x;
    const int w    = tid >> 6;
    const int lane = tid & 63;
    const int quad = lane >> 4;
    const int l15  = lane & 15;

    if (mode == 2 && tid < 64) {          // 2*sigmoid(x[:,:32] @ Wgate[:,h])
        int row = row0 + tid;
        float z = 0.f;
        for (int j = 0; j < 32; ++j)
            z += tof(x[(long)row * 1024 + j]) * tof(Wgate[j * 4 + h]);
        gateS[tid] = 2.f / (1.f + __expf(-z));
    }

    f32x4 acc[4];
    for (int n = 0; n < 4; ++n) acc[n] = (f32x4){0.f, 0.f, 0.f, 0.f};

    const int ar = tid >> 2, ac = (tid & 3) * 8;   // A stage: 64x32
    const int br = tid >> 3, bc = (tid & 7) * 8;   // B stage: 32x64

    for (int kk = 0; kk < 1024; kk += 32) {
        *(bf16x8*)(&As[ar * 40 + ac]) = load8(&x[(long)(row0 + ar) * 1024 + kk + ac]);
        bf16x8 bv = load8(&Wp[(long)(kk + br) * ldw + col0 + bc]);
#pragma unroll
        for (int j = 0; j < 8; ++j) Bs[(bc + j) * 40 + br] = bv[j];
        __syncthreads();

        bf16x8 af = *(const bf16x8*)(&As[(w * 16 + l15) * 40 + quad * 8]);
#pragma unroll
        for (int n = 0; n < 4; ++n) {
            bf16x8 bfr = *(const bf16x8*)(&Bs[(n * 16 + l15) * 40 + quad * 8]);
            acc[n] = __builtin_amdgcn_mfma_f32_16x16x32_bf16(af, bfr, acc[n], 0, 0, 0);
        }
        __syncthreads();
    }

    const int rbase = w * 16 + quad * 4;
    if (mode < 2) {
#pragma unroll
        for (int r = 0; r < 4; ++r) {
            int row = row0 + rbase + r;
            int b = row >> 11, t = row & 2047;
            float c0 = tof(cosp[t * 32 + l15]);
            float c1 = tof(cosp[t * 32 + 16 + l15]);
            float s0 = tof(sinp[t * 32 + l15]);
            float s1 = tof(sinp[t * 32 + 16 + l15]);
            float v0 =  c0 * acc[0][r] + s0 * acc[2][r];
            float v1 =  c1 * acc[1][r] + s1 * acc[3][r];
            float v2 = -s0 * acc[0][r] + c0 * acc[2][r];
            float v3 = -s1 * acc[1][r] + c1 * acc[3][r];
            float ss = v0 * v0 + v1 * v1 + v2 * v2 + v3 * v3;
            ss += __shfl_xor(ss, 1); ss += __shfl_xor(ss, 2);
            ss += __shfl_xor(ss, 4); ss += __shfl_xor(ss, 8);
            float sc = rsqrtf(ss * (1.f / 64.f) + 1.1920929e-7f);
            __bf16* dst = (mode == 0) ? qo : ko;
            int nh = (mode == 0) ? 16 : 4;
            long base = (((long)b * nh + h) * 2048 + t) * 64;
            dst[base + 0 * 16 + l15] = (__bf16)(v0 * sc);
            dst[base + 1 * 16 + l15] = (__bf16)(v1 * sc);
            dst[base + 2 * 16 + l15] = (__bf16)(v2 * sc);
            dst[base + 3 * 16 + l15] = (__bf16)(v3 * sc);
        }
    } else {
#pragma unroll
        for (int r = 0; r < 4; ++r) {
            int row = row0 + rbase + r;
            int b = row >> 11, t = row & 2047;
            float g = gateS[rbase + r];
            long vebase = ((long)(b * 2048 + t)) * 256 + h * 64;
            long obase  = (((long)b * 4 + h) * 2048 + t) * 64;
#pragma unroll
            for (int n = 0; n < 4; ++n) {
                float val = acc[n][r] + g * tof(ve[vebase + n * 16 + l15]);
                vo[obase + n * 16 + l15] = (__bf16)val;
            }
        }
    }
}

// ---------------------------------------------------------------------------
// Kernel 2: sliding-window causal GQA flash attention (bf16 internals only)
// Grid: (T/64, NH, B); 4 waves, each owns 16 q-rows
// ---------------------------------------------------------------------------
__global__ __launch_bounds__(256) void attn_kernel(
    const __bf16* __restrict__ qg, const __bf16* __restrict__ kg,
    const __bf16* __restrict__ vg, __bf16* __restrict__ yo,
    const int* __restrict__ winp)
{
    const int qt = blockIdx.x, hh = blockIdx.y, b = blockIdx.z;
    const int q0 = qt * 64;
    const int kvh = hh >> 2;
    const int W = winp[0];

    const int tid  = threadIdx.x;
    const int w    = tid >> 6;
    const int lane = tid & 63;
    const int quad = lane >> 4;
    const int l15  = lane & 15;

    __shared__ __bf16 Ks[64 * 72];
    __shared__ __bf16 Vs[64 * 72];
    __shared__ __bf16 Ps[4][16 * 72];

    const long qbase = (((long)b * 16 + hh) * 2048 + q0 + w * 16 + l15) * 64;
    bf16x8 qf0 = *(const bf16x8*)(&qg[qbase + quad * 8]);
    bf16x8 qf1 = *(const bf16x8*)(&qg[qbase + 32 + quad * 8]);

    f32x4 oacc[4];
    for (int n = 0; n < 4; ++n) oacc[n] = (f32x4){0.f, 0.f, 0.f, 0.f};
    float m_i[4], l_i[4];
    for (int r = 0; r < 4; ++r) { m_i[r] = -1e30f; l_i[r] = 0.f; }

    int lo = q0 - W;
    int kt_lo = lo > 0 ? (lo >> 6) : 0;
    const long kbase = ((long)b * 4 + kvh) * 2048 * 64;

    const int sr = tid >> 3, scc = (tid & 7) * 8;

    for (int kt = kt_lo; kt <= qt; ++kt) {
        int k0 = kt * 64;
#pragma unroll
        for (int i = 0; i < 2; ++i) {
            int r = sr + i * 32;
            *(bf16x8*)(&Ks[r * 72 + scc]) = *(const bf16x8*)(&kg[kbase + (long)(k0 + r) * 64 + scc]);
            *(bf16x8*)(&Vs[r * 72 + scc]) = *(const bf16x8*)(&vg[kbase + (long)(k0 + r) * 64 + scc]);
        }
        __syncthreads();

        f32x4 sacc[4];
        for (int n = 0; n < 4; ++n) sacc[n] = (f32x4){0.f, 0.f, 0.f, 0.f};
#pragma unroll
        for (int n = 0; n < 4; ++n) {
            bf16x8 b0 = *(const bf16x8*)(&Ks[(n * 16 + l15) * 72 + quad * 8]);
            sacc[n] = __builtin_amdgcn_mfma_f32_16x16x32_bf16(qf0, b0, sacc[n], 0, 0, 0);
            bf16x8 b1 = *(const bf16x8*)(&Ks[(n * 16 + l15) * 72 + 32 + quad * 8]);
            sacc[n] = __builtin_amdgcn_mfma_f32_16x16x32_bf16(qf1, b1, sacc[n], 0, 0, 0);
        }

#pragma unroll
        for (int r = 0; r < 4; ++r) {
            int row_g = q0 + w * 16 + quad * 4 + r;
            float sv[4];
            float mx = -1e30f;
#pragma unroll
            for (int n = 0; n < 4; ++n) {
                int col_g = k0 + n * 16 + l15;
                float s = sacc[n][r] * 0.125f;
                bool ok = (col_g <= row_g) && (row_g - col_g <= W);
                s = ok ? s : -1e30f;
                sv[n] = s;
                mx = fmaxf(mx, s);
            }
            mx = fmaxf(mx, __shfl_xor(mx, 1)); mx = fmaxf(mx, __shfl_xor(mx, 2));
            mx = fmaxf(mx, __shfl_xor(mx, 4)); mx = fmaxf(mx, __shfl_xor(mx, 8));
            float m_new = fmaxf(m_i[r], mx);
            float alpha = __expf(m_i[r] - m_new);
            float psum = 0.f;
#pragma unroll
            for (int n = 0; n < 4; ++n) {
                float p = __expf(sv[n] - m_new);
                psum += p;
                Ps[w][(quad * 4 + r) * 72 + n * 16 + l15] = (__bf16)p;
            }
            psum += __shfl_xor(psum, 1); psum += __shfl_xor(psum, 2);
            psum += __shfl_xor(psum, 4); psum += __shfl_xor(psum, 8);
            l_i[r] = l_i[r] * alpha + psum;
            m_i[r] = m_new;
#pragma unroll
            for (int n = 0; n < 4; ++n) oacc[n][r] *= alpha;
        }

        __syncthreads();   // Ps C-layout write -> A-layout read (cross-lane via LDS)

#pragma unroll
        for (int ks = 0; ks < 2; ++ks) {
            bf16x8 pf = *(const bf16x8*)(&Ps[w][l15 * 72 + ks * 32 + quad * 8]);
#pragma unroll
            for (int n = 0; n < 4; ++n) {
                bf16x8 bv;
#pragma unroll
                for (int j = 0; j < 8; ++j)
                    bv[j] = Vs[(ks * 32 + quad * 8 + j) * 72 + n * 16 + l15];
                oacc[n] = __builtin_amdgcn_mfma_f32_16x16x32_bf16(pf, bv, oacc[n], 0, 0, 0);
            }
        }
        __syncthreads();
    }

#pragma unroll
    for (int r = 0; r < 4; ++r) {
        int t = q0 + w * 16 + quad * 4 + r;
        float inv = 1.f / l_i[r];
        long base = ((long)(b * 2048 + t)) * 1024 + hh * 64;
#pragma unroll
        for (int n = 0; n < 4; ++n)
            yo[base + n * 16 + l15] = (__bf16)(oacc[n][r] * inv);
    }
}

// ---------------------------------------------------------------------------
// Kernel 3: output projection y(4096x1024) @ Wproj(1024x1024)
// ---------------------------------------------------------------------------
template <typename T>
__global__ __launch_bounds__(256) void proj_kernel(
    const __bf16* __restrict__ y, const T* __restrict__ Wp,
    T* __restrict__ out, const int* __restrict__ flag)
{
    if (*flag != (int)(sizeof(T) == 4)) return;

    const int row0 = blockIdx.x * 64;
    const int col0 = blockIdx.y * 64;
    __shared__ __bf16 As[64 * 40];
    __shared__ __bf16 Bs[64 * 40];

    const int tid  = threadIdx.x;
    const int w    = tid >> 6;
    const int lane = tid & 63;
    const int quad = lane >> 4;
    const int l15  = lane & 15;

    f32x4 acc[4];
    for (int n = 0; n < 4; ++n) acc[n] = (f32x4){0.f, 0.f, 0.f, 0.f};

    const int ar = tid >> 2, ac = (tid & 3) * 8;
    const int br = tid >> 3, bc = (tid & 7) * 8;

    for (int kk = 0; kk < 1024; kk += 32) {
        *(bf16x8*)(&As[ar * 40 + ac]) = *(const bf16x8*)(&y[(long)(row0 + ar) * 1024 + kk + ac]);
        bf16x8 bv = load8(&Wp[(long)(kk + br) * 1024 + col0 + bc]);
#pragma unroll
        for (int j = 0; j < 8; ++j) Bs[(bc + j) * 40 + br] = bv[j];
        __syncthreads();

        bf16x8 af = *(const bf16x8*)(&As[(w * 16 + l15) * 40 + quad * 8]);
#pragma unroll
        for (int n = 0; n < 4; ++n) {
            bf16x8 bfr = *(const bf16x8*)(&Bs[(n * 16 + l15) * 40 + quad * 8]);
            acc[n] = __builtin_amdgcn_mfma_f32_16x16x32_bf16(af, bfr, acc[n], 0, 0, 0);
        }
        __syncthreads();
    }

#pragma unroll
    for (int r = 0; r < 4; ++r) {
        int row = row0 + w * 16 + quad * 4 + r;
#pragma unroll
        for (int n = 0; n < 4; ++n)
            out[(long)row * 1024 + col0 + n * 16 + l15] = (T)acc[n][r];
    }
}

extern "C" void kernel_launch(void* const* d_in, const int* in_sizes, int n_in,
                              void* d_out, int out_size, void* d_ws, size_t ws_size,
                              hipStream_t stream) {
    const int* win = (const int*)d_in[9];

    int*    flag = (int*)d_ws;
    __bf16* q_ws = (__bf16*)((char*)d_ws + 256);        // (2,16,2048,64)
    __bf16* k_ws = q_ws + (size_t)2 * 16 * 2048 * 64;   // (2,4,2048,64)
    __bf16* v_ws = k_ws + (size_t)2 * 4 * 2048 * 64;    // (2,4,2048,64)
    __bf16* y_ws = v_ws + (size_t)2 * 4 * 2048 * 64;    // (2,2048,1024)

    sniff_kernel<<<1, 64, 0, stream>>>((const unsigned short*)d_in[0], flag);

    qkv_kernel<float><<<dim3(64, 24), 256, 0, stream>>>(
        (const float*)d_in[0], (const float*)d_in[1], (const float*)d_in[2],
        (const float*)d_in[3], (const float*)d_in[4], (const float*)d_in[5],
        (const float*)d_in[6], (const float*)d_in[8], q_ws, k_ws, v_ws, flag);
    qkv_kernel<__bf16><<<dim3(64, 24), 256, 0, stream>>>(
        (const __bf16*)d_in[0], (const __bf16*)d_in[1], (const __bf16*)d_in[2],
        (const __bf16*)d_in[3], (const __bf16*)d_in[4], (const __bf16*)d_in[5],
        (const __bf16*)d_in[6], (const __bf16*)d_in[8], q_ws, k_ws, v_ws, flag);

    attn_kernel<<<dim3(32, 16, 2), 256, 0, stream>>>(q_ws, k_ws, v_ws, y_ws, win);

    proj_kernel<float><<<dim3(64, 16), 256, 0, stream>>>(
        y_ws, (const float*)d_in[7], (float*)d_out, flag);
    proj_kernel<__bf16><<<dim3(64, 16), 256, 0, stream>>>(
        y_ws, (const __bf16*)d_in[7], (__bf16*)d_out, flag);
}

// Round 3
// 240.664 us; speedup vs baseline: 1.3146x; 1.3146x over previous
//
#include <hip/hip_runtime.h>

// (B,T,C)=(2,2048,1024), NH=16, NKV=4, HD=64, VEC=32
typedef __bf16 bf16x8 __attribute__((ext_vector_type(8)));
typedef float f32x4 __attribute__((ext_vector_type(4)));

__device__ inline float tof(float v) { return v; }
__device__ inline float tof(__bf16 v) { return (float)v; }

__device__ inline bf16x8 load8(const __bf16* p) { return *(const bf16x8*)p; }
__device__ inline bf16x8 load8(const float* p) {
    const float4 a = *(const float4*)p;
    const float4 b = *(const float4*)(p + 4);
    bf16x8 r;
    r[0] = (__bf16)a.x; r[1] = (__bf16)a.y; r[2] = (__bf16)a.z; r[3] = (__bf16)a.w;
    r[4] = (__bf16)b.x; r[5] = (__bf16)b.y; r[6] = (__bf16)b.z; r[7] = (__bf16)b.w;
    return r;
}

// ---------------------------------------------------------------------------
// Kernel 0: dtype sniffer (bf16 vs fp32 input buffers)
// ---------------------------------------------------------------------------
__global__ void sniff_kernel(const unsigned short* __restrict__ xs, int* flag) {
    if (threadIdx.x != 0) return;
    int bad = 0;
    for (int i = 0; i < 512; ++i) {
        unsigned int f = ((unsigned int)xs[i]) << 16;
        float v = __uint_as_float(f);
        float a = fabsf(v);
        if (!(a <= 1e4f) || (a != 0.f && a < 1e-6f)) bad++;
    }
    *flag = (bad > 32) ? 1 : 0;
}

// ---------------------------------------------------------------------------
// Kernel 1: prep — convert x/ve/cos/sin, transpose weights to B^T bf16, gate.
// Grid: 3280 blocks. [0,2624) convert, [2624,3264) transpose, [3264,3280) gate
// ---------------------------------------------------------------------------
template <typename T>
__global__ __launch_bounds__(256) void prep_kernel(
    const T* __restrict__ x, const T* __restrict__ ve,
    const T* __restrict__ cosp, const T* __restrict__ sinp,
    const T* __restrict__ Wq, const T* __restrict__ Wk,
    const T* __restrict__ Wv, const T* __restrict__ Wp, const T* __restrict__ Wg,
    __bf16* __restrict__ xb, __bf16* __restrict__ veb,
    float* __restrict__ cosf_, float* __restrict__ sinf_,
    __bf16* __restrict__ WqT, __bf16* __restrict__ WkT,
    __bf16* __restrict__ WvT, __bf16* __restrict__ WpT,
    float* __restrict__ gate, const int* __restrict__ flag)
{
    if (*flag != (int)(sizeof(T) == 4)) return;
    __shared__ __bf16 tile[64 * 72];
    const int b = blockIdx.x, tid = threadIdx.x;

    if (b < 2624) {                       // elementwise convert, 8 elems/thread
        int g = b * 256 + tid;
        if (g < 524288) {
            *(bf16x8*)(xb + (size_t)g * 8) = load8(x + (size_t)g * 8);
        } else if (g < 655360) {
            int gg = g - 524288;
            *(bf16x8*)(veb + (size_t)gg * 8) = load8(ve + (size_t)gg * 8);
        } else if (g < 663552) {
            int gg = g - 655360;
            const T* s = cosp + (size_t)gg * 8; float* d = cosf_ + (size_t)gg * 8;
#pragma unroll
            for (int j = 0; j < 8; ++j) d[j] = tof(s[j]);
        } else {
            int gg = g - 663552;
            const T* s = sinp + (size_t)gg * 8; float* d = sinf_ + (size_t)gg * 8;
#pragma unroll
            for (int j = 0; j < 8; ++j) d[j] = tof(s[j]);
        }
    } else if (b < 3264) {                // 64x64 tile transpose: W(K x N) -> WT(N x K)
        int idx = b - 2624;
        const T* src; __bf16* dst; int C;
        if (idx < 256)      { src = Wq; dst = WqT; C = 1024; }
        else if (idx < 320) { src = Wk; dst = WkT; C = 256;  idx -= 256; }
        else if (idx < 384) { src = Wv; dst = WvT; C = 256;  idx -= 320; }
        else                { src = Wp; dst = WpT; C = 1024; idx -= 384; }
        const int ctiles = C >> 6;
        const int r0 = (idx / ctiles) * 64, c0 = (idx % ctiles) * 64;
#pragma unroll
        for (int i = 0; i < 2; ++i) {
            int c = tid + i * 256, ir = c >> 3, ic = (c & 7) * 8;
            *(bf16x8*)(&tile[ir * 72 + ic]) = load8(src + (size_t)(r0 + ir) * C + c0 + ic);
        }
        __syncthreads();
#pragma unroll
        for (int i = 0; i < 2; ++i) {
            int c = tid + i * 256, orr = c >> 3, okc = (c & 7) * 8;
            bf16x8 v;
#pragma unroll
            for (int j = 0; j < 8; ++j) v[j] = tile[(okc + j) * 72 + orr];
            *(bf16x8*)(dst + (size_t)(c0 + orr) * 1024 + r0 + okc) = v;
        }
    } else {                              // gate = 2*sigmoid(x[:, :32] @ Wgate)
        int r = (b - 3264) * 256 + tid;
        float z[4] = {0.f, 0.f, 0.f, 0.f};
        for (int j = 0; j < 32; ++j) {
            float xv = tof(x[(size_t)r * 1024 + j]);
#pragma unroll
            for (int h = 0; h < 4; ++h) z[h] += xv * tof(Wg[j * 4 + h]);
        }
#pragma unroll
        for (int h = 0; h < 4; ++h) gate[r * 4 + h] = 2.f / (1.f + __expf(-z[h]));
    }
}

// ---------------------------------------------------------------------------
// Kernel 2: QKV GEMM, 128x128 tiles + fused gate*ve / RoPE / RMSNorm epilogue
// Grid: (4096/128, 12). cb<8: q, cb<10: k, else v. All bf16, B^T layout.
// ---------------------------------------------------------------------------
__global__ __launch_bounds__(256) void qkv_kernel(
    const __bf16* __restrict__ xb,
    const __bf16* __restrict__ WqT, const __bf16* __restrict__ WkT,
    const __bf16* __restrict__ WvT, const __bf16* __restrict__ veb,
    const float* __restrict__ cosf_, const float* __restrict__ sinf_,
    const float* __restrict__ gate,
    __bf16* __restrict__ qo, __bf16* __restrict__ ko, __bf16* __restrict__ vo)
{
    const int row0 = blockIdx.x * 128;
    const int cb = blockIdx.y;
    const __bf16* BT; int col0, mode;
    if (cb < 8)       { BT = WqT; col0 = cb * 128;        mode = 0; }
    else if (cb < 10) { BT = WkT; col0 = (cb - 8) * 128;  mode = 1; }
    else              { BT = WvT; col0 = (cb - 10) * 128; mode = 2; }

    __shared__ __bf16 As[128 * 40];
    __shared__ __bf16 Bs[128 * 40];

    const int tid  = threadIdx.x;
    const int w    = tid >> 6;
    const int lane = tid & 63;
    const int quad = lane >> 4;
    const int l15  = lane & 15;
    const int wr   = (w >> 1) * 64, wc = (w & 1) * 64;

    f32x4 acc[4][4];
#pragma unroll
    for (int mi = 0; mi < 4; ++mi)
#pragma unroll
        for (int nj = 0; nj < 4; ++nj) acc[mi][nj] = (f32x4){0.f, 0.f, 0.f, 0.f};

    for (int kk = 0; kk < 1024; kk += 32) {
#pragma unroll
        for (int i = 0; i < 2; ++i) {
            int c = tid + i * 256, rr = c >> 2, kc = (c & 3) * 8;
            *(bf16x8*)(&As[rr * 40 + kc]) = *(const bf16x8*)(&xb[(size_t)(row0 + rr) * 1024 + kk + kc]);
            *(bf16x8*)(&Bs[rr * 40 + kc]) = *(const bf16x8*)(&BT[(size_t)(col0 + rr) * 1024 + kk + kc]);
        }
        __syncthreads();
        bf16x8 a[4], bfr[4];
#pragma unroll
        for (int mi = 0; mi < 4; ++mi) a[mi]  = *(const bf16x8*)(&As[(wr + mi * 16 + l15) * 40 + quad * 8]);
#pragma unroll
        for (int nj = 0; nj < 4; ++nj) bfr[nj] = *(const bf16x8*)(&Bs[(wc + nj * 16 + l15) * 40 + quad * 8]);
#pragma unroll
        for (int mi = 0; mi < 4; ++mi)
#pragma unroll
            for (int nj = 0; nj < 4; ++nj)
                acc[mi][nj] = __builtin_amdgcn_mfma_f32_16x16x32_bf16(a[mi], bfr[nj], acc[mi][nj], 0, 0, 0);
        __syncthreads();
    }

    const int h = (col0 + wc) >> 6;    // head within q (0..15) or k/v (0..3)
    if (mode < 2) {
        __bf16* dst = (mode == 0) ? qo : ko;
        const int nh = (mode == 0) ? 16 : 4;
#pragma unroll
        for (int mi = 0; mi < 4; ++mi) {
#pragma unroll
            for (int r = 0; r < 4; ++r) {
                int row = row0 + wr + mi * 16 + quad * 4 + r;
                int b = row >> 11, t = row & 2047;
                float c0 = cosf_[t * 32 + l15];
                float c1 = cosf_[t * 32 + 16 + l15];
                float s0 = sinf_[t * 32 + l15];
                float s1 = sinf_[t * 32 + 16 + l15];
                float v0 =  c0 * acc[mi][0][r] + s0 * acc[mi][2][r];
                float v1 =  c1 * acc[mi][1][r] + s1 * acc[mi][3][r];
                float v2 = -s0 * acc[mi][0][r] + c0 * acc[mi][2][r];
                float v3 = -s1 * acc[mi][1][r] + c1 * acc[mi][3][r];
                float ss = v0 * v0 + v1 * v1 + v2 * v2 + v3 * v3;
                ss += __shfl_xor(ss, 1); ss += __shfl_xor(ss, 2);
                ss += __shfl_xor(ss, 4); ss += __shfl_xor(ss, 8);
                float sc = rsqrtf(ss * (1.f / 64.f) + 1.1920929e-7f);
                size_t base = (((size_t)b * nh + h) * 2048 + t) * 64;
                dst[base + 0 * 16 + l15] = (__bf16)(v0 * sc);
                dst[base + 1 * 16 + l15] = (__bf16)(v1 * sc);
                dst[base + 2 * 16 + l15] = (__bf16)(v2 * sc);
                dst[base + 3 * 16 + l15] = (__bf16)(v3 * sc);
            }
        }
    } else {
#pragma unroll
        for (int mi = 0; mi < 4; ++mi) {
#pragma unroll
            for (int r = 0; r < 4; ++r) {
                int row = row0 + wr + mi * 16 + quad * 4 + r;
                int b = row >> 11, t = row & 2047;
                float g = gate[row * 4 + h];
                size_t obase = (((size_t)b * 4 + h) * 2048 + t) * 64;
#pragma unroll
                for (int nj = 0; nj < 4; ++nj) {
                    float val = acc[mi][nj][r] + g * tof(veb[(size_t)row * 256 + h * 64 + nj * 16 + l15]);
                    vo[obase + nj * 16 + l15] = (__bf16)val;
                }
            }
        }
    }
}

// ---------------------------------------------------------------------------
// Kernel 3: sliding-window causal GQA flash attention. V staged transposed.
// Grid: (T/64, NH, B); 4 waves, each owns 16 q-rows
// ---------------------------------------------------------------------------
__global__ __launch_bounds__(256) void attn_kernel(
    const __bf16* __restrict__ qg, const __bf16* __restrict__ kg,
    const __bf16* __restrict__ vg, __bf16* __restrict__ yo,
    const int* __restrict__ winp)
{
    const int qt = blockIdx.x, hh = blockIdx.y, b = blockIdx.z;
    const int q0 = qt * 64;
    const int kvh = hh >> 2;
    const int W = winp[0];

    const int tid  = threadIdx.x;
    const int w    = tid >> 6;
    const int lane = tid & 63;
    const int quad = lane >> 4;
    const int l15  = lane & 15;

    __shared__ __bf16 Ks[64 * 72];     // [t][d]
    __shared__ __bf16 Vt[64 * 72];     // [d][t]  (transposed!)
    __shared__ __bf16 Ps[4][16 * 72];

    const size_t qbase = (((size_t)b * 16 + hh) * 2048 + q0 + w * 16 + l15) * 64;
    bf16x8 qf0 = *(const bf16x8*)(&qg[qbase + quad * 8]);
    bf16x8 qf1 = *(const bf16x8*)(&qg[qbase + 32 + quad * 8]);

    f32x4 oacc[4];
#pragma unroll
    for (int n = 0; n < 4; ++n) oacc[n] = (f32x4){0.f, 0.f, 0.f, 0.f};
    float m_i[4], l_i[4];
#pragma unroll
    for (int r = 0; r < 4; ++r) { m_i[r] = -1e30f; l_i[r] = 0.f; }

    int lo = q0 - W;
    int kt_lo = lo > 0 ? (lo >> 6) : 0;
    const size_t kbase = ((size_t)b * 4 + kvh) * 2048 * 64;

    const int sr = tid >> 3, scc = (tid & 7) * 8;

    for (int kt = kt_lo; kt <= qt; ++kt) {
        const int k0 = kt * 64;
        const bool need_mask = (kt == qt) || (q0 + 63 - k0 > W);
#pragma unroll
        for (int i = 0; i < 2; ++i) {
            int r = sr + i * 32;
            *(bf16x8*)(&Ks[r * 72 + scc]) = *(const bf16x8*)(&kg[kbase + (size_t)(k0 + r) * 64 + scc]);
            int c = tid + i * 256, t = c & 63, d0 = (c >> 6) * 8;
            bf16x8 vv = *(const bf16x8*)(&vg[kbase + (size_t)(k0 + t) * 64 + d0]);
#pragma unroll
            for (int j = 0; j < 8; ++j) Vt[(d0 + j) * 72 + t] = vv[j];
        }
        __syncthreads();

        f32x4 sacc[4];
#pragma unroll
        for (int n = 0; n < 4; ++n) sacc[n] = (f32x4){0.f, 0.f, 0.f, 0.f};
#pragma unroll
        for (int n = 0; n < 4; ++n) {
            bf16x8 b0 = *(const bf16x8*)(&Ks[(n * 16 + l15) * 72 + quad * 8]);
            sacc[n] = __builtin_amdgcn_mfma_f32_16x16x32_bf16(qf0, b0, sacc[n], 0, 0, 0);
            bf16x8 b1 = *(const bf16x8*)(&Ks[(n * 16 + l15) * 72 + 32 + quad * 8]);
            sacc[n] = __builtin_amdgcn_mfma_f32_16x16x32_bf16(qf1, b1, sacc[n], 0, 0, 0);
        }

#pragma unroll
        for (int r = 0; r < 4; ++r) {
            int row_g = q0 + w * 16 + quad * 4 + r;
            float sv[4];
            float mx = -1e30f;
            if (need_mask) {
#pragma unroll
                for (int n = 0; n < 4; ++n) {
                    int col_g = k0 + n * 16 + l15;
                    float s = sacc[n][r] * 0.125f;
                    bool ok = (col_g <= row_g) && (row_g - col_g <= W);
                    s = ok ? s : -1e30f;
                    sv[n] = s; mx = fmaxf(mx, s);
                }
            } else {
#pragma unroll
                for (int n = 0; n < 4; ++n) { sv[n] = sacc[n][r] * 0.125f; mx = fmaxf(mx, sv[n]); }
            }
            mx = fmaxf(mx, __shfl_xor(mx, 1)); mx = fmaxf(mx, __shfl_xor(mx, 2));
            mx = fmaxf(mx, __shfl_xor(mx, 4)); mx = fmaxf(mx, __shfl_xor(mx, 8));
            float m_new = fmaxf(m_i[r], mx);
            float alpha = __expf(m_i[r] - m_new);
            float psum = 0.f;
#pragma unroll
            for (int n = 0; n < 4; ++n) {
                float p = __expf(sv[n] - m_new);
                psum += p;
                Ps[w][(quad * 4 + r) * 72 + n * 16 + l15] = (__bf16)p;
            }
            psum += __shfl_xor(psum, 1); psum += __shfl_xor(psum, 2);
            psum += __shfl_xor(psum, 4); psum += __shfl_xor(psum, 8);
            l_i[r] = l_i[r] * alpha + psum;
            m_i[r] = m_new;
#pragma unroll
            for (int n = 0; n < 4; ++n) oacc[n][r] *= alpha;
        }

        __syncthreads();   // Ps C-layout write -> A-layout read

#pragma unroll
        for (int ks = 0; ks < 2; ++ks) {
            bf16x8 pf = *(const bf16x8*)(&Ps[w][l15 * 72 + ks * 32 + quad * 8]);
#pragma unroll
            for (int n = 0; n < 4; ++n) {
                bf16x8 bv = *(const bf16x8*)(&Vt[(n * 16 + l15) * 72 + ks * 32 + quad * 8]);
                oacc[n] = __builtin_amdgcn_mfma_f32_16x16x32_bf16(pf, bv, oacc[n], 0, 0, 0);
            }
        }
        __syncthreads();   // protect Ks/Vt before next tile's staging
    }

#pragma unroll
    for (int r = 0; r < 4; ++r) {
        int t = q0 + w * 16 + quad * 4 + r;
        float inv = 1.f / l_i[r];
        size_t base = ((size_t)(b * 2048 + t)) * 1024 + hh * 64;
#pragma unroll
        for (int n = 0; n < 4; ++n)
            yo[base + n * 16 + l15] = (__bf16)(oacc[n][r] * inv);
    }
}

// ---------------------------------------------------------------------------
// Kernel 4: output projection, 128x128 tiles, y(4096x1024) @ Wproj
// ---------------------------------------------------------------------------
template <typename T>
__global__ __launch_bounds__(256) void proj_kernel(
    const __bf16* __restrict__ y, const __bf16* __restrict__ WpT,
    T* __restrict__ out, const int* __restrict__ flag)
{
    if (*flag != (int)(sizeof(T) == 4)) return;
    const int row0 = blockIdx.x * 128;
    const int col0 = blockIdx.y * 128;
    __shared__ __bf16 As[128 * 40];
    __shared__ __bf16 Bs[128 * 40];

    const int tid  = threadIdx.x;
    const int w    = tid >> 6;
    const int lane = tid & 63;
    const int quad = lane >> 4;
    const int l15  = lane & 15;
    const int wr   = (w >> 1) * 64, wc = (w & 1) * 64;

    f32x4 acc[4][4];
#pragma unroll
    for (int mi = 0; mi < 4; ++mi)
#pragma unroll
        for (int nj = 0; nj < 4; ++nj) acc[mi][nj] = (f32x4){0.f, 0.f, 0.f, 0.f};

    for (int kk = 0; kk < 1024; kk += 32) {
#pragma unroll
        for (int i = 0; i < 2; ++i) {
            int c = tid + i * 256, rr = c >> 2, kc = (c & 3) * 8;
            *(bf16x8*)(&As[rr * 40 + kc]) = *(const bf16x8*)(&y[(size_t)(row0 + rr) * 1024 + kk + kc]);
            *(bf16x8*)(&Bs[rr * 40 + kc]) = *(const bf16x8*)(&WpT[(size_t)(col0 + rr) * 1024 + kk + kc]);
        }
        __syncthreads();
        bf16x8 a[4], bfr[4];
#pragma unroll
        for (int mi = 0; mi < 4; ++mi) a[mi]  = *(const bf16x8*)(&As[(wr + mi * 16 + l15) * 40 + quad * 8]);
#pragma unroll
        for (int nj = 0; nj < 4; ++nj) bfr[nj] = *(const bf16x8*)(&Bs[(wc + nj * 16 + l15) * 40 + quad * 8]);
#pragma unroll
        for (int mi = 0; mi < 4; ++mi)
#pragma unroll
            for (int nj = 0; nj < 4; ++nj)
                acc[mi][nj] = __builtin_amdgcn_mfma_f32_16x16x32_bf16(a[mi], bfr[nj], acc[mi][nj], 0, 0, 0);
        __syncthreads();
    }

#pragma unroll
    for (int mi = 0; mi < 4; ++mi)
#pragma unroll
        for (int r = 0; r < 4; ++r) {
            int row = row0 + wr + mi * 16 + quad * 4 + r;
#pragma unroll
            for (int nj = 0; nj < 4; ++nj)
                out[(size_t)row * 1024 + col0 + wc + nj * 16 + l15] = (T)acc[mi][nj][r];
        }
}

extern "C" void kernel_launch(void* const* d_in, const int* in_sizes, int n_in,
                              void* d_out, int out_size, void* d_ws, size_t ws_size,
                              hipStream_t stream) {
    const int* win = (const int*)d_in[9];

    char* p = (char*)d_ws;
    int*    flag = (int*)p;                    p += 256;
    __bf16* q_ws = (__bf16*)p;                 p += (size_t)4194304 * 2;
    __bf16* k_ws = (__bf16*)p;                 p += (size_t)1048576 * 2;
    __bf16* v_ws = (__bf16*)p;                 p += (size_t)1048576 * 2;
    __bf16* y_ws = (__bf16*)p;                 p += (size_t)4194304 * 2;
    __bf16* xb   = (__bf16*)p;                 p += (size_t)4194304 * 2;
    __bf16* veb  = (__bf16*)p;                 p += (size_t)1048576 * 2;
    __bf16* WqT  = (__bf16*)p;                 p += (size_t)1048576 * 2;
    __bf16* WkT  = (__bf16*)p;                 p += (size_t)262144 * 2;
    __bf16* WvT  = (__bf16*)p;                 p += (size_t)262144 * 2;
    __bf16* WpT  = (__bf16*)p;                 p += (size_t)1048576 * 2;
    float*  cosf_ = (float*)p;                 p += (size_t)65536 * 4;
    float*  sinf_ = (float*)p;                 p += (size_t)65536 * 4;
    float*  gate  = (float*)p;                 p += (size_t)16384 * 4;

    sniff_kernel<<<1, 64, 0, stream>>>((const unsigned short*)d_in[0], flag);

    prep_kernel<float><<<3280, 256, 0, stream>>>(
        (const float*)d_in[0], (const float*)d_in[1], (const float*)d_in[2],
        (const float*)d_in[3], (const float*)d_in[4], (const float*)d_in[5],
        (const float*)d_in[6], (const float*)d_in[7], (const float*)d_in[8],
        xb, veb, cosf_, sinf_, WqT, WkT, WvT, WpT, gate, flag);
    prep_kernel<__bf16><<<3280, 256, 0, stream>>>(
        (const __bf16*)d_in[0], (const __bf16*)d_in[1], (const __bf16*)d_in[2],
        (const __bf16*)d_in[3], (const __bf16*)d_in[4], (const __bf16*)d_in[5],
        (const __bf16*)d_in[6], (const __bf16*)d_in[7], (const __bf16*)d_in[8],
        xb, veb, cosf_, sinf_, WqT, WkT, WvT, WpT, gate, flag);

    qkv_kernel<<<dim3(32, 12), 256, 0, stream>>>(xb, WqT, WkT, WvT, veb,
                                                 cosf_, sinf_, gate, q_ws, k_ws, v_ws);

    attn_kernel<<<dim3(32, 16, 2), 256, 0, stream>>>(q_ws, k_ws, v_ws, y_ws, win);

    proj_kernel<float><<<dim3(32, 8), 256, 0, stream>>>(y_ws, WpT, (float*)d_out, flag);
    proj_kernel<__bf16><<<dim3(32, 8), 256, 0, stream>>>(y_ws, WpT, (__bf16*)d_out, flag);
}

// Round 5
// 232.053 us; speedup vs baseline: 1.3634x; 1.0371x over previous
//
#include <hip/hip_runtime.h>

// (B,T,C)=(2,2048,1024), NH=16, NKV=4, HD=64, VEC=32
typedef __bf16 bf16x8 __attribute__((ext_vector_type(8)));
typedef float f32x4 __attribute__((ext_vector_type(4)));

__device__ inline float tof(float v) { return v; }
__device__ inline float tof(__bf16 v) { return (float)v; }

__device__ inline bf16x8 load8(const __bf16* p) { return *(const bf16x8*)p; }
__device__ inline bf16x8 load8(const float* p) {
    const float4 a = *(const float4*)p;
    const float4 b = *(const float4*)(p + 4);
    bf16x8 r;
    r[0] = (__bf16)a.x; r[1] = (__bf16)a.y; r[2] = (__bf16)a.z; r[3] = (__bf16)a.w;
    r[4] = (__bf16)b.x; r[5] = (__bf16)b.y; r[6] = (__bf16)b.z; r[7] = (__bf16)b.w;
    return r;
}

// async global->LDS, 16B per lane (dest must be base + lane*16 contiguous)
__device__ __forceinline__ void cp16(__bf16* lds, const __bf16* g) {
    __builtin_amdgcn_global_load_lds((__attribute__((address_space(1))) void*)g,
                                     (__attribute__((address_space(3))) void*)lds,
                                     16, 0, 0);
}

// ---------------------------------------------------------------------------
// Kernel 0: dtype sniffer (bf16 vs fp32 input buffers)
// ---------------------------------------------------------------------------
__global__ void sniff_kernel(const unsigned short* __restrict__ xs, int* flag) {
    if (threadIdx.x != 0) return;
    int bad = 0;
    for (int i = 0; i < 512; ++i) {
        unsigned int f = ((unsigned int)xs[i]) << 16;
        float v = __uint_as_float(f);
        float a = fabsf(v);
        if (!(a <= 1e4f) || (a != 0.f && a < 1e-6f)) bad++;
    }
    *flag = (bad > 32) ? 1 : 0;
}

// ---------------------------------------------------------------------------
// Kernel 1: prep — convert x/ve/cos/sin, transpose weights to B^T bf16, gate.
// ---------------------------------------------------------------------------
template <typename T>
__global__ __launch_bounds__(256) void prep_kernel(
    const T* __restrict__ x, const T* __restrict__ ve,
    const T* __restrict__ cosp, const T* __restrict__ sinp,
    const T* __restrict__ Wq, const T* __restrict__ Wk,
    const T* __restrict__ Wv, const T* __restrict__ Wp, const T* __restrict__ Wg,
    __bf16* __restrict__ xb, __bf16* __restrict__ veb,
    float* __restrict__ cosf_, float* __restrict__ sinf_,
    __bf16* __restrict__ WqT, __bf16* __restrict__ WkT,
    __bf16* __restrict__ WvT, __bf16* __restrict__ WpT,
    float* __restrict__ gate, const int* __restrict__ flag)
{
    if (*flag != (int)(sizeof(T) == 4)) return;
    __shared__ __bf16 tile[64 * 72];
    const int b = blockIdx.x, tid = threadIdx.x;

    if (b < 2624) {
        int g = b * 256 + tid;
        if (g < 524288) {
            *(bf16x8*)(xb + (size_t)g * 8) = load8(x + (size_t)g * 8);
        } else if (g < 655360) {
            int gg = g - 524288;
            *(bf16x8*)(veb + (size_t)gg * 8) = load8(ve + (size_t)gg * 8);
        } else if (g < 663552) {
            int gg = g - 655360;
            const T* s = cosp + (size_t)gg * 8; float* d = cosf_ + (size_t)gg * 8;
#pragma unroll
            for (int j = 0; j < 8; ++j) d[j] = tof(s[j]);
        } else {
            int gg = g - 663552;
            const T* s = sinp + (size_t)gg * 8; float* d = sinf_ + (size_t)gg * 8;
#pragma unroll
            for (int j = 0; j < 8; ++j) d[j] = tof(s[j]);
        }
    } else if (b < 3264) {                // 64x64 tile transpose
        int idx = b - 2624;
        const T* src; __bf16* dst; int C;
        if (idx < 256)      { src = Wq; dst = WqT; C = 1024; }
        else if (idx < 320) { src = Wk; dst = WkT; C = 256;  idx -= 256; }
        else if (idx < 384) { src = Wv; dst = WvT; C = 256;  idx -= 320; }
        else                { src = Wp; dst = WpT; C = 1024; idx -= 384; }
        const int ctiles = C >> 6;
        const int r0 = (idx / ctiles) * 64, c0 = (idx % ctiles) * 64;
#pragma unroll
        for (int i = 0; i < 2; ++i) {
            int c = tid + i * 256, ir = c >> 3, ic = (c & 7) * 8;
            *(bf16x8*)(&tile[ir * 72 + ic]) = load8(src + (size_t)(r0 + ir) * C + c0 + ic);
        }
        __syncthreads();
#pragma unroll
        for (int i = 0; i < 2; ++i) {
            int c = tid + i * 256, orr = c >> 3, okc = (c & 7) * 8;
            bf16x8 v;
#pragma unroll
            for (int j = 0; j < 8; ++j) v[j] = tile[(okc + j) * 72 + orr];
            *(bf16x8*)(dst + (size_t)(c0 + orr) * 1024 + r0 + okc) = v;
        }
    } else {                              // gate = 2*sigmoid(x[:, :32] @ Wgate)
        int r = (b - 3264) * 256 + tid;
        float z[4] = {0.f, 0.f, 0.f, 0.f};
        for (int j = 0; j < 32; ++j) {
            float xv = tof(x[(size_t)r * 1024 + j]);
#pragma unroll
            for (int h = 0; h < 4; ++h) z[h] += xv * tof(Wg[j * 4 + h]);
        }
#pragma unroll
        for (int h = 0; h < 4; ++h) gate[r * 4 + h] = 2.f / (1.f + __expf(-z[h]));
    }
}

// ---------------------------------------------------------------------------
// Kernel 2: QKV GEMM, 128x128 tiles, global_load_lds staging (m97 structure)
// + fused gate*ve / RoPE / RMSNorm epilogue
// ---------------------------------------------------------------------------
__global__ __launch_bounds__(256) void qkv_kernel(
    const __bf16* __restrict__ xb,
    const __bf16* __restrict__ WqT, const __bf16* __restrict__ WkT,
    const __bf16* __restrict__ WvT, const __bf16* __restrict__ veb,
    const float* __restrict__ cosf_, const float* __restrict__ sinf_,
    const float* __restrict__ gate,
    __bf16* __restrict__ qo, __bf16* __restrict__ ko, __bf16* __restrict__ vo)
{
    const int row0 = blockIdx.x * 128;
    const int cb = blockIdx.y;
    const __bf16* BT; int col0, mode;
    if (cb < 8)       { BT = WqT; col0 = cb * 128;        mode = 0; }
    else if (cb < 10) { BT = WkT; col0 = (cb - 8) * 128;  mode = 1; }
    else              { BT = WvT; col0 = (cb - 10) * 128; mode = 2; }

    __shared__ __align__(16) __bf16 As[128 * 32];   // unpadded: required by cp16
    __shared__ __align__(16) __bf16 Bs[128 * 32];

    const int tid  = threadIdx.x;
    const int w    = tid >> 6;
    const int lane = tid & 63;
    const int quad = lane >> 4;
    const int l15  = lane & 15;
    const int wr   = (w >> 1) * 64, wc = (w & 1) * 64;

    f32x4 acc[4][4];
#pragma unroll
    for (int mi = 0; mi < 4; ++mi)
#pragma unroll
        for (int nj = 0; nj < 4; ++nj) acc[mi][nj] = (f32x4){0.f, 0.f, 0.f, 0.f};

    for (int kk = 0; kk < 1024; kk += 32) {
#pragma unroll
        for (int i = 0; i < 2; ++i) {
            int c = i * 256 + (w << 6) + lane;     // lane-contiguous per wave
            int rr = c >> 2, kc = (c & 3) << 3;
            cp16(&As[c << 3], &xb[(size_t)(row0 + rr) * 1024 + kk + kc]);
            cp16(&Bs[c << 3], &BT[(size_t)(col0 + rr) * 1024 + kk + kc]);
        }
        __syncthreads();
        bf16x8 a[4], bfr[4];
#pragma unroll
        for (int mi = 0; mi < 4; ++mi) a[mi]  = *(const bf16x8*)(&As[(wr + mi * 16 + l15) * 32 + quad * 8]);
#pragma unroll
        for (int nj = 0; nj < 4; ++nj) bfr[nj] = *(const bf16x8*)(&Bs[(wc + nj * 16 + l15) * 32 + quad * 8]);
#pragma unroll
        for (int mi = 0; mi < 4; ++mi)
#pragma unroll
            for (int nj = 0; nj < 4; ++nj)
                acc[mi][nj] = __builtin_amdgcn_mfma_f32_16x16x32_bf16(a[mi], bfr[nj], acc[mi][nj], 0, 0, 0);
        __syncthreads();
    }

    const int h = (col0 + wc) >> 6;
    if (mode < 2) {
        __bf16* dst = (mode == 0) ? qo : ko;
        const int nh = (mode == 0) ? 16 : 4;
#pragma unroll
        for (int mi = 0; mi < 4; ++mi) {
#pragma unroll
            for (int r = 0; r < 4; ++r) {
                int row = row0 + wr + mi * 16 + quad * 4 + r;
                int b = row >> 11, t = row & 2047;
                float c0 = cosf_[t * 32 + l15];
                float c1 = cosf_[t * 32 + 16 + l15];
                float s0 = sinf_[t * 32 + l15];
                float s1 = sinf_[t * 32 + 16 + l15];
                float v0 =  c0 * acc[mi][0][r] + s0 * acc[mi][2][r];
                float v1 =  c1 * acc[mi][1][r] + s1 * acc[mi][3][r];
                float v2 = -s0 * acc[mi][0][r] + c0 * acc[mi][2][r];
                float v3 = -s1 * acc[mi][1][r] + c1 * acc[mi][3][r];
                float ss = v0 * v0 + v1 * v1 + v2 * v2 + v3 * v3;
                ss += __shfl_xor(ss, 1); ss += __shfl_xor(ss, 2);
                ss += __shfl_xor(ss, 4); ss += __shfl_xor(ss, 8);
                float sc = rsqrtf(ss * (1.f / 64.f) + 1.1920929e-7f);
                size_t base = (((size_t)b * nh + h) * 2048 + t) * 64;
                dst[base + 0 * 16 + l15] = (__bf16)(v0 * sc);
                dst[base + 1 * 16 + l15] = (__bf16)(v1 * sc);
                dst[base + 2 * 16 + l15] = (__bf16)(v2 * sc);
                dst[base + 3 * 16 + l15] = (__bf16)(v3 * sc);
            }
        }
    } else {
#pragma unroll
        for (int mi = 0; mi < 4; ++mi) {
#pragma unroll
            for (int r = 0; r < 4; ++r) {
                int row = row0 + wr + mi * 16 + quad * 4 + r;
                int b = row >> 11, t = row & 2047;
                float g = gate[row * 4 + h];
                size_t obase = (((size_t)b * 4 + h) * 2048 + t) * 64;
#pragma unroll
                for (int nj = 0; nj < 4; ++nj) {
                    float val = acc[mi][nj][r] + g * tof(veb[(size_t)row * 256 + h * 64 + nj * 16 + l15]);
                    vo[obase + nj * 16 + l15] = (__bf16)val;
                }
            }
        }
    }
}

// ---------------------------------------------------------------------------
// Kernel 3: sliding-window causal GQA flash attention.
// Bounded-score softmax (RMSNorm => |s|<=8): no running max, no rescale,
// deferred l-reduction. K/V double-buffered, ONE barrier per K-tile.
// Ps is wave-private: write->read ordered by lgkmcnt(0) only.
// ---------------------------------------------------------------------------
__global__ __launch_bounds__(256) void attn_kernel(
    const __bf16* __restrict__ qg, const __bf16* __restrict__ kg,
    const __bf16* __restrict__ vg, __bf16* __restrict__ yo,
    const int* __restrict__ winp)
{
    const int qt = blockIdx.x, hh = blockIdx.y, b = blockIdx.z;
    const int q0 = qt * 64;
    const int kvh = hh >> 2;
    const int W = winp[0];

    const int tid  = threadIdx.x;
    const int w    = tid >> 6;
    const int lane = tid & 63;
    const int quad = lane >> 4;
    const int l15  = lane & 15;

    __shared__ __align__(16) __bf16 Ks[2][64 * 72];   // [t][d]
    __shared__ __align__(16) __bf16 Vt[2][64 * 72];   // [d][t]
    __shared__ __align__(16) __bf16 Ps[4][16 * 72];   // per-wave P

    const size_t qbase = (((size_t)b * 16 + hh) * 2048 + q0 + w * 16 + l15) * 64;
    bf16x8 qf0 = *(const bf16x8*)(&qg[qbase + quad * 8]);
    bf16x8 qf1 = *(const bf16x8*)(&qg[qbase + 32 + quad * 8]);

    f32x4 oacc[4];
#pragma unroll
    for (int n = 0; n < 4; ++n) oacc[n] = (f32x4){0.f, 0.f, 0.f, 0.f};
    float lsum[4] = {0.f, 0.f, 0.f, 0.f};

    int lo = q0 - W;
    const int kt_lo = lo > 0 ? (lo >> 6) : 0;
    const size_t kbase = ((size_t)b * 4 + kvh) * 2048 * 64;

    {   // prologue: stage tile kt_lo into buffer 0
        const int k0 = kt_lo * 64;
#pragma unroll
        for (int i = 0; i < 2; ++i) {
            int c = i * 256 + tid;
            int rk = c >> 3, dk = (c & 7) * 8;          // K: row slow, d fast
            bf16x8 kv = *(const bf16x8*)(&kg[kbase + (size_t)(k0 + rk) * 64 + dk]);
            *(bf16x8*)(&Ks[0][rk * 72 + dk]) = kv;
            int rv = c & 63, dv = ((c >> 6) & 7) * 8;   // V: row fast -> conflict-free transpose stores
            bf16x8 vv = *(const bf16x8*)(&vg[kbase + (size_t)(k0 + rv) * 64 + dv]);
#pragma unroll
            for (int j = 0; j < 8; ++j) Vt[0][(dv + j) * 72 + rv] = vv[j];
        }
    }
    __syncthreads();

    int cur = 0;
    for (int kt = kt_lo; kt <= qt; ++kt) {
        const int k0 = kt * 64;
        const bool need_mask = (kt == qt) || (q0 + 63 - k0 > W);
        const bool pf = (kt < qt);
        bf16x8 pk[2], pv[2];
        if (pf) {       // prefetch next tile into registers (in flight during QK)
            const int k0n = k0 + 64;
#pragma unroll
            for (int i = 0; i < 2; ++i) {
                int c = i * 256 + tid;
                int rk = c >> 3, dk = (c & 7) * 8;
                pk[i] = *(const bf16x8*)(&kg[kbase + (size_t)(k0n + rk) * 64 + dk]);
                int rv = c & 63, dv = ((c >> 6) & 7) * 8;
                pv[i] = *(const bf16x8*)(&vg[kbase + (size_t)(k0n + rv) * 64 + dv]);
            }
        }

        // QK^T
        f32x4 sacc[4];
#pragma unroll
        for (int n = 0; n < 4; ++n) sacc[n] = (f32x4){0.f, 0.f, 0.f, 0.f};
        const __bf16* Kc = &Ks[cur][0];
#pragma unroll
        for (int n = 0; n < 4; ++n) {
            bf16x8 b0 = *(const bf16x8*)(&Kc[(n * 16 + l15) * 72 + quad * 8]);
            sacc[n] = __builtin_amdgcn_mfma_f32_16x16x32_bf16(qf0, b0, sacc[n], 0, 0, 0);
            bf16x8 b1 = *(const bf16x8*)(&Kc[(n * 16 + l15) * 72 + 32 + quad * 8]);
            sacc[n] = __builtin_amdgcn_mfma_f32_16x16x32_bf16(qf1, b1, sacc[n], 0, 0, 0);
        }

        // bounded-score softmax: p = exp(s/8 - 8) = exp2(s*log2e/8 - 8*log2e)
#pragma unroll
        for (int r = 0; r < 4; ++r) {
            const int row_g = q0 + w * 16 + quad * 4 + r;
#pragma unroll
            for (int n = 0; n < 4; ++n) {
                float p = exp2f(fmaf(sacc[n][r], 0.18033688f, -11.5415603f));
                if (need_mask) {
                    int col_g = k0 + n * 16 + l15;
                    bool ok = (col_g <= row_g) && (row_g - col_g <= W);
                    p = ok ? p : 0.f;
                }
                lsum[r] += p;
                Ps[w][(quad * 4 + r) * 72 + n * 16 + l15] = (__bf16)p;
            }
        }
        asm volatile("s_waitcnt lgkmcnt(0)" ::: "memory");   // wave-local Ps ordering

        // PV
        const __bf16* Vc = &Vt[cur][0];
#pragma unroll
        for (int ks = 0; ks < 2; ++ks) {
            bf16x8 pfr = *(const bf16x8*)(&Ps[w][l15 * 72 + ks * 32 + quad * 8]);
#pragma unroll
            for (int n = 0; n < 4; ++n) {
                bf16x8 bv = *(const bf16x8*)(&Vc[(n * 16 + l15) * 72 + ks * 32 + quad * 8]);
                oacc[n] = __builtin_amdgcn_mfma_f32_16x16x32_bf16(pfr, bv, oacc[n], 0, 0, 0);
            }
        }

        if (pf) {       // write prefetched tile into the other buffer
            const int nxt = cur ^ 1;
#pragma unroll
            for (int i = 0; i < 2; ++i) {
                int c = i * 256 + tid;
                int rk = c >> 3, dk = (c & 7) * 8;
                *(bf16x8*)(&Ks[nxt][rk * 72 + dk]) = pk[i];
                int rv = c & 63, dv = ((c >> 6) & 7) * 8;
#pragma unroll
                for (int j = 0; j < 8; ++j) Vt[nxt][(dv + j) * 72 + rv] = pv[i][j];
            }
            cur = nxt;
        }
        __syncthreads();   // single barrier per tile
    }

#pragma unroll
    for (int r = 0; r < 4; ++r) {
        float l = lsum[r];
        l += __shfl_xor(l, 1); l += __shfl_xor(l, 2);
        l += __shfl_xor(l, 4); l += __shfl_xor(l, 8);
        float inv = 1.f / l;
        int t = q0 + w * 16 + quad * 4 + r;
        size_t base = ((size_t)(b * 2048 + t)) * 1024 + hh * 64;
#pragma unroll
        for (int n = 0; n < 4; ++n)
            yo[base + n * 16 + l15] = (__bf16)(oacc[n][r] * inv);
    }
}

// ---------------------------------------------------------------------------
// Kernel 4: output projection, 128x128 tiles, global_load_lds staging
// ---------------------------------------------------------------------------
template <typename T>
__global__ __launch_bounds__(256) void proj_kernel(
    const __bf16* __restrict__ y, const __bf16* __restrict__ WpT,
    T* __restrict__ out, const int* __restrict__ flag)
{
    if (*flag != (int)(sizeof(T) == 4)) return;
    const int row0 = blockIdx.x * 128;
    const int col0 = blockIdx.y * 128;
    __shared__ __align__(16) __bf16 As[128 * 32];
    __shared__ __align__(16) __bf16 Bs[128 * 32];

    const int tid  = threadIdx.x;
    const int w    = tid >> 6;
    const int lane = tid & 63;
    const int quad = lane >> 4;
    const int l15  = lane & 15;
    const int wr   = (w >> 1) * 64, wc = (w & 1) * 64;

    f32x4 acc[4][4];
#pragma unroll
    for (int mi = 0; mi < 4; ++mi)
#pragma unroll
        for (int nj = 0; nj < 4; ++nj) acc[mi][nj] = (f32x4){0.f, 0.f, 0.f, 0.f};

    for (int kk = 0; kk < 1024; kk += 32) {
#pragma unroll
        for (int i = 0; i < 2; ++i) {
            int c = i * 256 + (w << 6) + lane;
            int rr = c >> 2, kc = (c & 3) << 3;
            cp16(&As[c << 3], &y[(size_t)(row0 + rr) * 1024 + kk + kc]);
            cp16(&Bs[c << 3], &WpT[(size_t)(col0 + rr) * 1024 + kk + kc]);
        }
        __syncthreads();
        bf16x8 a[4], bfr[4];
#pragma unroll
        for (int mi = 0; mi < 4; ++mi) a[mi]  = *(const bf16x8*)(&As[(wr + mi * 16 + l15) * 32 + quad * 8]);
#pragma unroll
        for (int nj = 0; nj < 4; ++nj) bfr[nj] = *(const bf16x8*)(&Bs[(wc + nj * 16 + l15) * 32 + quad * 8]);
#pragma unroll
        for (int mi = 0; mi < 4; ++mi)
#pragma unroll
            for (int nj = 0; nj < 4; ++nj)
                acc[mi][nj] = __builtin_amdgcn_mfma_f32_16x16x32_bf16(a[mi], bfr[nj], acc[mi][nj], 0, 0, 0);
        __syncthreads();
    }

#pragma unroll
    for (int mi = 0; mi < 4; ++mi)
#pragma unroll
        for (int r = 0; r < 4; ++r) {
            int row = row0 + wr + mi * 16 + quad * 4 + r;
#pragma unroll
            for (int nj = 0; nj < 4; ++nj)
                out[(size_t)row * 1024 + col0 + wc + nj * 16 + l15] = (T)acc[mi][nj][r];
        }
}

extern "C" void kernel_launch(void* const* d_in, const int* in_sizes, int n_in,
                              void* d_out, int out_size, void* d_ws, size_t ws_size,
                              hipStream_t stream) {
    const int* win = (const int*)d_in[9];

    char* p = (char*)d_ws;
    int*    flag = (int*)p;                    p += 256;
    __bf16* q_ws = (__bf16*)p;                 p += (size_t)4194304 * 2;
    __bf16* k_ws = (__bf16*)p;                 p += (size_t)1048576 * 2;
    __bf16* v_ws = (__bf16*)p;                 p += (size_t)1048576 * 2;
    __bf16* y_ws = (__bf16*)p;                 p += (size_t)4194304 * 2;
    __bf16* xb   = (__bf16*)p;                 p += (size_t)4194304 * 2;
    __bf16* veb  = (__bf16*)p;                 p += (size_t)1048576 * 2;
    __bf16* WqT  = (__bf16*)p;                 p += (size_t)1048576 * 2;
    __bf16* WkT  = (__bf16*)p;                 p += (size_t)262144 * 2;
    __bf16* WvT  = (__bf16*)p;                 p += (size_t)262144 * 2;
    __bf16* WpT  = (__bf16*)p;                 p += (size_t)1048576 * 2;
    float*  cosf_ = (float*)p;                 p += (size_t)65536 * 4;
    float*  sinf_ = (float*)p;                 p += (size_t)65536 * 4;
    float*  gate  = (float*)p;                 p += (size_t)16384 * 4;

    sniff_kernel<<<1, 64, 0, stream>>>((const unsigned short*)d_in[0], flag);

    prep_kernel<float><<<3280, 256, 0, stream>>>(
        (const float*)d_in[0], (const float*)d_in[1], (const float*)d_in[2],
        (const float*)d_in[3], (const float*)d_in[4], (const float*)d_in[5],
        (const float*)d_in[6], (const float*)d_in[7], (const float*)d_in[8],
        xb, veb, cosf_, sinf_, WqT, WkT, WvT, WpT, gate, flag);
    prep_kernel<__bf16><<<3280, 256, 0, stream>>>(
        (const __bf16*)d_in[0], (const __bf16*)d_in[1], (const __bf16*)d_in[2],
        (const __bf16*)d_in[3], (const __bf16*)d_in[4], (const __bf16*)d_in[5],
        (const __bf16*)d_in[6], (const __bf16*)d_in[7], (const __bf16*)d_in[8],
        xb, veb, cosf_, sinf_, WqT, WkT, WvT, WpT, gate, flag);

    qkv_kernel<<<dim3(32, 12), 256, 0, stream>>>(xb, WqT, WkT, WvT, veb,
                                                 cosf_, sinf_, gate, q_ws, k_ws, v_ws);

    attn_kernel<<<dim3(32, 16, 2), 256, 0, stream>>>(q_ws, k_ws, v_ws, y_ws, win);

    proj_kernel<float><<<dim3(32, 8), 256, 0, stream>>>(y_ws, WpT, (float*)d_out, flag);
    proj_kernel<__bf16><<<dim3(32, 8), 256, 0, stream>>>(y_ws, WpT, (__bf16*)d_out, flag);
}

// Round 6
// 213.248 us; speedup vs baseline: 1.4836x; 1.0882x over previous
//
#include <hip/hip_runtime.h>

// (B,T,C)=(2,2048,1024), NH=16, NKV=4, HD=64, VEC=32
typedef __bf16 bf16x8 __attribute__((ext_vector_type(8)));
typedef float f32x4 __attribute__((ext_vector_type(4)));

__device__ inline float tof(float v) { return v; }
__device__ inline float tof(__bf16 v) { return (float)v; }

__device__ inline bf16x8 load8(const __bf16* p) { return *(const bf16x8*)p; }
__device__ inline bf16x8 load8(const float* p) {
    const float4 a = *(const float4*)p;
    const float4 b = *(const float4*)(p + 4);
    bf16x8 r;
    r[0] = (__bf16)a.x; r[1] = (__bf16)a.y; r[2] = (__bf16)a.z; r[3] = (__bf16)a.w;
    r[4] = (__bf16)b.x; r[5] = (__bf16)b.y; r[6] = (__bf16)b.z; r[7] = (__bf16)b.w;
    return r;
}

// async global->LDS, 16B per lane (dest must be base + lane*16 contiguous)
__device__ __forceinline__ void cp16(__bf16* lds, const __bf16* g) {
    __builtin_amdgcn_global_load_lds((__attribute__((address_space(1))) void*)g,
                                     (__attribute__((address_space(3))) void*)lds,
                                     16, 0, 0);
}

// ---------------------------------------------------------------------------
// Kernel 0: dtype sniffer (bf16 vs fp32 input buffers)
// ---------------------------------------------------------------------------
__global__ void sniff_kernel(const unsigned short* __restrict__ xs, int* flag) {
    if (threadIdx.x != 0) return;
    int bad = 0;
    for (int i = 0; i < 512; ++i) {
        unsigned int f = ((unsigned int)xs[i]) << 16;
        float v = __uint_as_float(f);
        float a = fabsf(v);
        if (!(a <= 1e4f) || (a != 0.f && a < 1e-6f)) bad++;
    }
    *flag = (bad > 32) ? 1 : 0;
}

// ---------------------------------------------------------------------------
// Kernel 1: prep — convert x/ve/cos/sin, transpose weights to B^T bf16, gate.
// Single launch; dtype resolved by runtime uniform branch on *flag.
// ---------------------------------------------------------------------------
template <typename T>
__device__ __forceinline__ void prep_body(
    const T* __restrict__ x, const T* __restrict__ ve,
    const T* __restrict__ cosp, const T* __restrict__ sinp,
    const T* __restrict__ Wq, const T* __restrict__ Wk,
    const T* __restrict__ Wv, const T* __restrict__ Wp, const T* __restrict__ Wg,
    __bf16* __restrict__ xb, __bf16* __restrict__ veb,
    float* __restrict__ cosf_, float* __restrict__ sinf_,
    __bf16* __restrict__ WqT, __bf16* __restrict__ WkT,
    __bf16* __restrict__ WvT, __bf16* __restrict__ WpT,
    float* __restrict__ gate, __bf16* tile)
{
    const int b = blockIdx.x, tid = threadIdx.x;

    if (b < 2624) {
        int g = b * 256 + tid;
        if (g < 524288) {
            *(bf16x8*)(xb + (size_t)g * 8) = load8(x + (size_t)g * 8);
        } else if (g < 655360) {
            int gg = g - 524288;
            *(bf16x8*)(veb + (size_t)gg * 8) = load8(ve + (size_t)gg * 8);
        } else if (g < 663552) {
            int gg = g - 655360;
            const T* s = cosp + (size_t)gg * 8; float* d = cosf_ + (size_t)gg * 8;
#pragma unroll
            for (int j = 0; j < 8; ++j) d[j] = tof(s[j]);
        } else {
            int gg = g - 663552;
            const T* s = sinp + (size_t)gg * 8; float* d = sinf_ + (size_t)gg * 8;
#pragma unroll
            for (int j = 0; j < 8; ++j) d[j] = tof(s[j]);
        }
    } else if (b < 3264) {                // 64x64 tile transpose
        int idx = b - 2624;
        const T* src; __bf16* dst; int C;
        if (idx < 256)      { src = Wq; dst = WqT; C = 1024; }
        else if (idx < 320) { src = Wk; dst = WkT; C = 256;  idx -= 256; }
        else if (idx < 384) { src = Wv; dst = WvT; C = 256;  idx -= 320; }
        else                { src = Wp; dst = WpT; C = 1024; idx -= 384; }
        const int ctiles = C >> 6;
        const int r0 = (idx / ctiles) * 64, c0 = (idx % ctiles) * 64;
#pragma unroll
        for (int i = 0; i < 2; ++i) {
            int c = tid + i * 256, ir = c >> 3, ic = (c & 7) * 8;
            *(bf16x8*)(&tile[ir * 72 + ic]) = load8(src + (size_t)(r0 + ir) * C + c0 + ic);
        }
        __syncthreads();
#pragma unroll
        for (int i = 0; i < 2; ++i) {
            int c = tid + i * 256, orr = c >> 3, okc = (c & 7) * 8;
            bf16x8 v;
#pragma unroll
            for (int j = 0; j < 8; ++j) v[j] = tile[(okc + j) * 72 + orr];
            *(bf16x8*)(dst + (size_t)(c0 + orr) * 1024 + r0 + okc) = v;
        }
    } else {                              // gate = 2*sigmoid(x[:, :32] @ Wgate)
        int r = (b - 3264) * 256 + tid;
        float z[4] = {0.f, 0.f, 0.f, 0.f};
        for (int j = 0; j < 32; ++j) {
            float xv = tof(x[(size_t)r * 1024 + j]);
#pragma unroll
            for (int h = 0; h < 4; ++h) z[h] += xv * tof(Wg[j * 4 + h]);
        }
#pragma unroll
        for (int h = 0; h < 4; ++h) gate[r * 4 + h] = 2.f / (1.f + __expf(-z[h]));
    }
}

__global__ __launch_bounds__(256) void prep_kernel(
    const void* x, const void* ve, const void* cosp, const void* sinp,
    const void* Wq, const void* Wk, const void* Wv, const void* Wp, const void* Wg,
    __bf16* xb, __bf16* veb, float* cosf_, float* sinf_,
    __bf16* WqT, __bf16* WkT, __bf16* WvT, __bf16* WpT,
    float* gate, const int* __restrict__ flag)
{
    __shared__ __bf16 tile[64 * 72];
    if (*flag) {
        prep_body<float>((const float*)x, (const float*)ve, (const float*)cosp,
                         (const float*)sinp, (const float*)Wq, (const float*)Wk,
                         (const float*)Wv, (const float*)Wp, (const float*)Wg,
                         xb, veb, cosf_, sinf_, WqT, WkT, WvT, WpT, gate, tile);
    } else {
        prep_body<__bf16>((const __bf16*)x, (const __bf16*)ve, (const __bf16*)cosp,
                          (const __bf16*)sinp, (const __bf16*)Wq, (const __bf16*)Wk,
                          (const __bf16*)Wv, (const __bf16*)Wp, (const __bf16*)Wg,
                          xb, veb, cosf_, sinf_, WqT, WkT, WvT, WpT, gate, tile);
    }
}

// ---------------------------------------------------------------------------
// Kernel 2: QKV GEMM, 128x64 tiles (one head per block), wave = 32 rows x 64
// cols so RoPE pairs + RMSNorm stay in-wave. global_load_lds staging.
// Grid: (32, 24). cb<16: q head cb; cb<20: k head cb-16; else v head cb-20.
// ---------------------------------------------------------------------------
__global__ __launch_bounds__(256) void qkv_kernel(
    const __bf16* __restrict__ xb,
    const __bf16* __restrict__ WqT, const __bf16* __restrict__ WkT,
    const __bf16* __restrict__ WvT, const __bf16* __restrict__ veb,
    const float* __restrict__ cosf_, const float* __restrict__ sinf_,
    const float* __restrict__ gate,
    __bf16* __restrict__ qo, __bf16* __restrict__ ko, __bf16* __restrict__ vo)
{
    const int row0 = blockIdx.x * 128;
    const int cb = blockIdx.y;
    const __bf16* BT; int col0, h, mode;
    if (cb < 16)      { BT = WqT; col0 = cb * 64;        h = cb;      mode = 0; }
    else if (cb < 20) { BT = WkT; col0 = (cb - 16) * 64; h = cb - 16; mode = 1; }
    else              { BT = WvT; col0 = (cb - 20) * 64; h = cb - 20; mode = 2; }

    __shared__ __align__(16) __bf16 As[128 * 32];
    __shared__ __align__(16) __bf16 Bs[64 * 32];

    const int tid  = threadIdx.x;
    const int w    = tid >> 6;
    const int lane = tid & 63;
    const int quad = lane >> 4;
    const int l15  = lane & 15;
    const int wr   = w * 32;            // wave owns rows wr..wr+31, all 64 cols

    f32x4 acc[2][4];
#pragma unroll
    for (int mi = 0; mi < 2; ++mi)
#pragma unroll
        for (int nj = 0; nj < 4; ++nj) acc[mi][nj] = (f32x4){0.f, 0.f, 0.f, 0.f};

    for (int kk = 0; kk < 1024; kk += 32) {
#pragma unroll
        for (int i = 0; i < 2; ++i) {
            int c = i * 256 + (w << 6) + lane;
            int rr = c >> 2, kc = (c & 3) << 3;
            cp16(&As[c << 3], &xb[(size_t)(row0 + rr) * 1024 + kk + kc]);
        }
        {
            int c = (w << 6) + lane;
            int rr = c >> 2, kc = (c & 3) << 3;
            cp16(&Bs[c << 3], &BT[(size_t)(col0 + rr) * 1024 + kk + kc]);
        }
        __syncthreads();
        bf16x8 a[2], bfr[4];
#pragma unroll
        for (int mi = 0; mi < 2; ++mi) a[mi]  = *(const bf16x8*)(&As[(wr + mi * 16 + l15) * 32 + quad * 8]);
#pragma unroll
        for (int nj = 0; nj < 4; ++nj) bfr[nj] = *(const bf16x8*)(&Bs[(nj * 16 + l15) * 32 + quad * 8]);
#pragma unroll
        for (int mi = 0; mi < 2; ++mi)
#pragma unroll
            for (int nj = 0; nj < 4; ++nj)
                acc[mi][nj] = __builtin_amdgcn_mfma_f32_16x16x32_bf16(a[mi], bfr[nj], acc[mi][nj], 0, 0, 0);
        __syncthreads();
    }

    if (mode < 2) {
        __bf16* dst = (mode == 0) ? qo : ko;
        const int nh = (mode == 0) ? 16 : 4;
#pragma unroll
        for (int mi = 0; mi < 2; ++mi) {
#pragma unroll
            for (int r = 0; r < 4; ++r) {
                int row = row0 + wr + mi * 16 + quad * 4 + r;
                int b = row >> 11, t = row & 2047;
                float c0 = cosf_[t * 32 + l15];
                float c1 = cosf_[t * 32 + 16 + l15];
                float s0 = sinf_[t * 32 + l15];
                float s1 = sinf_[t * 32 + 16 + l15];
                float v0 =  c0 * acc[mi][0][r] + s0 * acc[mi][2][r];
                float v1 =  c1 * acc[mi][1][r] + s1 * acc[mi][3][r];
                float v2 = -s0 * acc[mi][0][r] + c0 * acc[mi][2][r];
                float v3 = -s1 * acc[mi][1][r] + c1 * acc[mi][3][r];
                float ss = v0 * v0 + v1 * v1 + v2 * v2 + v3 * v3;
                ss += __shfl_xor(ss, 1); ss += __shfl_xor(ss, 2);
                ss += __shfl_xor(ss, 4); ss += __shfl_xor(ss, 8);
                float sc = rsqrtf(ss * (1.f / 64.f) + 1.1920929e-7f);
                size_t base = (((size_t)b * nh + h) * 2048 + t) * 64;
                dst[base + 0 * 16 + l15] = (__bf16)(v0 * sc);
                dst[base + 1 * 16 + l15] = (__bf16)(v1 * sc);
                dst[base + 2 * 16 + l15] = (__bf16)(v2 * sc);
                dst[base + 3 * 16 + l15] = (__bf16)(v3 * sc);
            }
        }
    } else {
#pragma unroll
        for (int mi = 0; mi < 2; ++mi) {
#pragma unroll
            for (int r = 0; r < 4; ++r) {
                int row = row0 + wr + mi * 16 + quad * 4 + r;
                int b = row >> 11, t = row & 2047;
                float g = gate[row * 4 + h];
                size_t obase = (((size_t)b * 4 + h) * 2048 + t) * 64;
#pragma unroll
                for (int nj = 0; nj < 4; ++nj) {
                    float val = acc[mi][nj][r] + g * tof(veb[(size_t)row * 256 + h * 64 + nj * 16 + l15]);
                    vo[obase + nj * 16 + l15] = (__bf16)val;
                }
            }
        }
    }
}

// ---------------------------------------------------------------------------
// Kernel 3: sliding-window causal GQA flash attention.
// Block = 128 q-rows x 1 head; wave owns 32 q-rows (2 Q-frag sets) so K/V
// staging + fragment reads amortize over 2x work. Bounded-score softmax,
// K/V double-buffered, one barrier per tile. Grid: (16, 16, 2).
// ---------------------------------------------------------------------------
__global__ __launch_bounds__(256) void attn_kernel(
    const __bf16* __restrict__ qg, const __bf16* __restrict__ kg,
    const __bf16* __restrict__ vg, __bf16* __restrict__ yo,
    const int* __restrict__ winp)
{
    const int q0 = blockIdx.x * 128;
    const int hh = blockIdx.y, b = blockIdx.z;
    const int kvh = hh >> 2;
    const int W = winp[0];

    const int tid  = threadIdx.x;
    const int w    = tid >> 6;
    const int lane = tid & 63;
    const int quad = lane >> 4;
    const int l15  = lane & 15;

    __shared__ __align__(16) __bf16 Ks[2][64 * 72];   // [t][d]
    __shared__ __align__(16) __bf16 Vt[2][64 * 72];   // [d][t]
    __shared__ __align__(16) __bf16 Ps[4][32 * 72];   // per-wave P (32 q-rows)

    bf16x8 qf[2][2];
#pragma unroll
    for (int i = 0; i < 2; ++i) {
        size_t qb = (((size_t)b * 16 + hh) * 2048 + q0 + w * 32 + i * 16 + l15) * 64;
        qf[i][0] = *(const bf16x8*)(&qg[qb + quad * 8]);
        qf[i][1] = *(const bf16x8*)(&qg[qb + 32 + quad * 8]);
    }

    f32x4 oacc[2][4];
    float lsum[2][4];
#pragma unroll
    for (int i = 0; i < 2; ++i)
#pragma unroll
        for (int n = 0; n < 4; ++n) {
            oacc[i][n] = (f32x4){0.f, 0.f, 0.f, 0.f};
            lsum[i][n] = 0.f;
        }

    const int lo = q0 - W;
    const int kt_lo = lo > 0 ? (lo >> 6) : 0;
    const int kt_hi = (q0 + 127) >> 6;
    const size_t kbase = ((size_t)b * 4 + kvh) * 2048 * 64;

    {   // prologue: stage tile kt_lo into buffer 0
        const int k0 = kt_lo * 64;
#pragma unroll
        for (int i = 0; i < 2; ++i) {
            int c = i * 256 + tid;
            int rk = c >> 3, dk = (c & 7) * 8;
            bf16x8 kv = *(const bf16x8*)(&kg[kbase + (size_t)(k0 + rk) * 64 + dk]);
            *(bf16x8*)(&Ks[0][rk * 72 + dk]) = kv;
            int rv = c & 63, dv = ((c >> 6) & 7) * 8;
            bf16x8 vv = *(const bf16x8*)(&vg[kbase + (size_t)(k0 + rv) * 64 + dv]);
#pragma unroll
            for (int j = 0; j < 8; ++j) Vt[0][(dv + j) * 72 + rv] = vv[j];
        }
    }
    __syncthreads();

    int cur = 0;
    for (int kt = kt_lo; kt <= kt_hi; ++kt) {
        const int k0 = kt * 64;
        const bool need_mask = (k0 + 63 > q0) || (q0 + 127 - k0 > W);
        const bool pf = (kt < kt_hi);
        bf16x8 pk[2], pv[2];
        if (pf) {       // register prefetch of next tile, in flight during QK/PV
            const int k0n = k0 + 64;
#pragma unroll
            for (int i = 0; i < 2; ++i) {
                int c = i * 256 + tid;
                int rk = c >> 3, dk = (c & 7) * 8;
                pk[i] = *(const bf16x8*)(&kg[kbase + (size_t)(k0n + rk) * 64 + dk]);
                int rv = c & 63, dv = ((c >> 6) & 7) * 8;
                pv[i] = *(const bf16x8*)(&vg[kbase + (size_t)(k0n + rv) * 64 + dv]);
            }
        }

        // QK^T: K-frags shared across both Q-frag sets
        f32x4 sacc[2][4];
#pragma unroll
        for (int i = 0; i < 2; ++i)
#pragma unroll
            for (int n = 0; n < 4; ++n) sacc[i][n] = (f32x4){0.f, 0.f, 0.f, 0.f};
        const __bf16* Kc = &Ks[cur][0];
#pragma unroll
        for (int n = 0; n < 4; ++n) {
            bf16x8 b0 = *(const bf16x8*)(&Kc[(n * 16 + l15) * 72 + quad * 8]);
            bf16x8 b1 = *(const bf16x8*)(&Kc[(n * 16 + l15) * 72 + 32 + quad * 8]);
#pragma unroll
            for (int i = 0; i < 2; ++i) {
                sacc[i][n] = __builtin_amdgcn_mfma_f32_16x16x32_bf16(qf[i][0], b0, sacc[i][n], 0, 0, 0);
                sacc[i][n] = __builtin_amdgcn_mfma_f32_16x16x32_bf16(qf[i][1], b1, sacc[i][n], 0, 0, 0);
            }
        }

        // bounded-score softmax: p = exp2(s*log2e/8 - 8*log2e)
#pragma unroll
        for (int i = 0; i < 2; ++i) {
#pragma unroll
            for (int r = 0; r < 4; ++r) {
                const int row_g = q0 + w * 32 + i * 16 + quad * 4 + r;
#pragma unroll
                for (int n = 0; n < 4; ++n) {
                    float p = exp2f(fmaf(sacc[i][n][r], 0.18033688f, -11.5415603f));
                    if (need_mask) {
                        int col_g = k0 + n * 16 + l15;
                        bool ok = (col_g <= row_g) && (row_g - col_g <= W);
                        p = ok ? p : 0.f;
                    }
                    lsum[i][r] += p;
                    Ps[w][(i * 16 + quad * 4 + r) * 72 + n * 16 + l15] = (__bf16)p;
                }
            }
        }
        asm volatile("s_waitcnt lgkmcnt(0)" ::: "memory");   // wave-local Ps ordering

        // PV: V-frags shared across both P-frag sets
        const __bf16* Vc = &Vt[cur][0];
#pragma unroll
        for (int ks = 0; ks < 2; ++ks) {
            bf16x8 pfr0 = *(const bf16x8*)(&Ps[w][l15 * 72 + ks * 32 + quad * 8]);
            bf16x8 pfr1 = *(const bf16x8*)(&Ps[w][(16 + l15) * 72 + ks * 32 + quad * 8]);
#pragma unroll
            for (int n = 0; n < 4; ++n) {
                bf16x8 bv = *(const bf16x8*)(&Vc[(n * 16 + l15) * 72 + ks * 32 + quad * 8]);
                oacc[0][n] = __builtin_amdgcn_mfma_f32_16x16x32_bf16(pfr0, bv, oacc[0][n], 0, 0, 0);
                oacc[1][n] = __builtin_amdgcn_mfma_f32_16x16x32_bf16(pfr1, bv, oacc[1][n], 0, 0, 0);
            }
        }

        if (pf) {       // commit prefetched tile to the other buffer
            const int nxt = cur ^ 1;
#pragma unroll
            for (int i = 0; i < 2; ++i) {
                int c = i * 256 + tid;
                int rk = c >> 3, dk = (c & 7) * 8;
                *(bf16x8*)(&Ks[nxt][rk * 72 + dk]) = pk[i];
                int rv = c & 63, dv = ((c >> 6) & 7) * 8;
#pragma unroll
                for (int j = 0; j < 8; ++j) Vt[nxt][(dv + j) * 72 + rv] = pv[i][j];
            }
            cur = nxt;
        }
        __syncthreads();   // single barrier per tile
    }

#pragma unroll
    for (int i = 0; i < 2; ++i) {
#pragma unroll
        for (int r = 0; r < 4; ++r) {
            float l = lsum[i][r];
            l += __shfl_xor(l, 1); l += __shfl_xor(l, 2);
            l += __shfl_xor(l, 4); l += __shfl_xor(l, 8);
            float inv = 1.f / l;
            int t = q0 + w * 32 + i * 16 + quad * 4 + r;
            size_t base = ((size_t)(b * 2048 + t)) * 1024 + hh * 64;
#pragma unroll
            for (int n = 0; n < 4; ++n)
                yo[base + n * 16 + l15] = (__bf16)(oacc[i][n][r] * inv);
        }
    }
}

// ---------------------------------------------------------------------------
// Kernel 4: output projection, 128x64 tiles, wave = 32x64. Single launch;
// output dtype resolved by runtime uniform branch. Grid: (32, 16).
// ---------------------------------------------------------------------------
__global__ __launch_bounds__(256) void proj_kernel(
    const __bf16* __restrict__ y, const __bf16* __restrict__ WpT,
    void* __restrict__ outp, const int* __restrict__ flag)
{
    const int isf32 = *flag;
    const int row0 = blockIdx.x * 128;
    const int col0 = blockIdx.y * 64;
    __shared__ __align__(16) __bf16 As[128 * 32];
    __shared__ __align__(16) __bf16 Bs[64 * 32];

    const int tid  = threadIdx.x;
    const int w    = tid >> 6;
    const int lane = tid & 63;
    const int quad = lane >> 4;
    const int l15  = lane & 15;
    const int wr   = w * 32;

    f32x4 acc[2][4];
#pragma unroll
    for (int mi = 0; mi < 2; ++mi)
#pragma unroll
        for (int nj = 0; nj < 4; ++nj) acc[mi][nj] = (f32x4){0.f, 0.f, 0.f, 0.f};

    for (int kk = 0; kk < 1024; kk += 32) {
#pragma unroll
        for (int i = 0; i < 2; ++i) {
            int c = i * 256 + (w << 6) + lane;
            int rr = c >> 2, kc = (c & 3) << 3;
            cp16(&As[c << 3], &y[(size_t)(row0 + rr) * 1024 + kk + kc]);
        }
        {
            int c = (w << 6) + lane;
            int rr = c >> 2, kc = (c & 3) << 3;
            cp16(&Bs[c << 3], &WpT[(size_t)(col0 + rr) * 1024 + kk + kc]);
        }
        __syncthreads();
        bf16x8 a[2], bfr[4];
#pragma unroll
        for (int mi = 0; mi < 2; ++mi) a[mi]  = *(const bf16x8*)(&As[(wr + mi * 16 + l15) * 32 + quad * 8]);
#pragma unroll
        for (int nj = 0; nj < 4; ++nj) bfr[nj] = *(const bf16x8*)(&Bs[(nj * 16 + l15) * 32 + quad * 8]);
#pragma unroll
        for (int mi = 0; mi < 2; ++mi)
#pragma unroll
            for (int nj = 0; nj < 4; ++nj)
                acc[mi][nj] = __builtin_amdgcn_mfma_f32_16x16x32_bf16(a[mi], bfr[nj], acc[mi][nj], 0, 0, 0);
        __syncthreads();
    }

#pragma unroll
    for (int mi = 0; mi < 2; ++mi)
#pragma unroll
        for (int r = 0; r < 4; ++r) {
            int row = row0 + wr + mi * 16 + quad * 4 + r;
            if (isf32) {
                float* out = (float*)outp;
#pragma unroll
                for (int nj = 0; nj < 4; ++nj)
                    out[(size_t)row * 1024 + col0 + nj * 16 + l15] = acc[mi][nj][r];
            } else {
                __bf16* out = (__bf16*)outp;
#pragma unroll
                for (int nj = 0; nj < 4; ++nj)
                    out[(size_t)row * 1024 + col0 + nj * 16 + l15] = (__bf16)acc[mi][nj][r];
            }
        }
}

extern "C" void kernel_launch(void* const* d_in, const int* in_sizes, int n_in,
                              void* d_out, int out_size, void* d_ws, size_t ws_size,
                              hipStream_t stream) {
    const int* win = (const int*)d_in[9];

    char* p = (char*)d_ws;
    int*    flag = (int*)p;                    p += 256;
    __bf16* q_ws = (__bf16*)p;                 p += (size_t)4194304 * 2;
    __bf16* k_ws = (__bf16*)p;                 p += (size_t)1048576 * 2;
    __bf16* v_ws = (__bf16*)p;                 p += (size_t)1048576 * 2;
    __bf16* y_ws = (__bf16*)p;                 p += (size_t)4194304 * 2;
    __bf16* xb   = (__bf16*)p;                 p += (size_t)4194304 * 2;
    __bf16* veb  = (__bf16*)p;                 p += (size_t)1048576 * 2;
    __bf16* WqT  = (__bf16*)p;                 p += (size_t)1048576 * 2;
    __bf16* WkT  = (__bf16*)p;                 p += (size_t)262144 * 2;
    __bf16* WvT  = (__bf16*)p;                 p += (size_t)262144 * 2;
    __bf16* WpT  = (__bf16*)p;                 p += (size_t)1048576 * 2;
    float*  cosf_ = (float*)p;                 p += (size_t)65536 * 4;
    float*  sinf_ = (float*)p;                 p += (size_t)65536 * 4;
    float*  gate  = (float*)p;                 p += (size_t)16384 * 4;

    sniff_kernel<<<1, 64, 0, stream>>>((const unsigned short*)d_in[0], flag);

    prep_kernel<<<3280, 256, 0, stream>>>(
        d_in[0], d_in[1], d_in[2], d_in[3], d_in[4], d_in[5], d_in[6], d_in[7],
        d_in[8], xb, veb, cosf_, sinf_, WqT, WkT, WvT, WpT, gate, flag);

    qkv_kernel<<<dim3(32, 24), 256, 0, stream>>>(xb, WqT, WkT, WvT, veb,
                                                 cosf_, sinf_, gate, q_ws, k_ws, v_ws);

    attn_kernel<<<dim3(16, 16, 2), 256, 0, stream>>>(q_ws, k_ws, v_ws, y_ws, win);

    proj_kernel<<<dim3(32, 16), 256, 0, stream>>>(y_ws, WpT, d_out, flag);
}

// Round 7
// 195.478 us; speedup vs baseline: 1.6185x; 1.0909x over previous
//
#include <hip/hip_runtime.h>

// (B,T,C)=(2,2048,1024), NH=16, NKV=4, HD=64, VEC=32
typedef __bf16 bf16x8 __attribute__((ext_vector_type(8)));
typedef __bf16 bf16x4 __attribute__((ext_vector_type(4)));
typedef float f32x4 __attribute__((ext_vector_type(4)));

__device__ inline float tof(float v) { return v; }
__device__ inline float tof(__bf16 v) { return (float)v; }

__device__ inline bf16x8 load8(const __bf16* p) { return *(const bf16x8*)p; }
__device__ inline bf16x8 load8(const float* p) {
    const float4 a = *(const float4*)p;
    const float4 b = *(const float4*)(p + 4);
    bf16x8 r;
    r[0] = (__bf16)a.x; r[1] = (__bf16)a.y; r[2] = (__bf16)a.z; r[3] = (__bf16)a.w;
    r[4] = (__bf16)b.x; r[5] = (__bf16)b.y; r[6] = (__bf16)b.z; r[7] = (__bf16)b.w;
    return r;
}

// async global->LDS, 16B per lane (dest = wave-uniform base + lane*16)
__device__ __forceinline__ void cp16(__bf16* lds, const __bf16* g) {
    __builtin_amdgcn_global_load_lds((__attribute__((address_space(1))) void*)g,
                                     (__attribute__((address_space(3))) void*)lds,
                                     16, 0, 0);
}

// ---------------------------------------------------------------------------
// Kernel 0: dtype sniffer (bf16 vs fp32 input buffers), parallel over 64 lanes
// ---------------------------------------------------------------------------
__global__ void sniff_kernel(const unsigned short* __restrict__ xs, int* flag) {
    int tid = threadIdx.x;
    int bad = 0;
    for (int i = tid; i < 512; i += 64) {
        unsigned int f = ((unsigned int)xs[i]) << 16;
        float v = __uint_as_float(f);
        float a = fabsf(v);
        if (!(a <= 1e4f) || (a != 0.f && a < 1e-6f)) bad++;
    }
    bad += __shfl_xor(bad, 1);  bad += __shfl_xor(bad, 2);
    bad += __shfl_xor(bad, 4);  bad += __shfl_xor(bad, 8);
    bad += __shfl_xor(bad, 16); bad += __shfl_xor(bad, 32);
    if (tid == 0) *flag = (bad > 32) ? 1 : 0;
}

// ---------------------------------------------------------------------------
// Kernel 1: prep — convert x/ve/cos/sin, transpose weights to B^T bf16, gate.
// ---------------------------------------------------------------------------
template <typename T>
__device__ __forceinline__ void prep_body(
    const T* __restrict__ x, const T* __restrict__ ve,
    const T* __restrict__ cosp, const T* __restrict__ sinp,
    const T* __restrict__ Wq, const T* __restrict__ Wk,
    const T* __restrict__ Wv, const T* __restrict__ Wp, const T* __restrict__ Wg,
    __bf16* __restrict__ xb, __bf16* __restrict__ veb,
    float* __restrict__ cosf_, float* __restrict__ sinf_,
    __bf16* __restrict__ WqT, __bf16* __restrict__ WkT,
    __bf16* __restrict__ WvT, __bf16* __restrict__ WpT,
    float* __restrict__ gate, __bf16* tile)
{
    const int b = blockIdx.x, tid = threadIdx.x;

    if (b < 2624) {
        int g = b * 256 + tid;
        if (g < 524288) {
            *(bf16x8*)(xb + (size_t)g * 8) = load8(x + (size_t)g * 8);
        } else if (g < 655360) {
            int gg = g - 524288;
            *(bf16x8*)(veb + (size_t)gg * 8) = load8(ve + (size_t)gg * 8);
        } else if (g < 663552) {
            int gg = g - 655360;
            const T* s = cosp + (size_t)gg * 8; float* d = cosf_ + (size_t)gg * 8;
#pragma unroll
            for (int j = 0; j < 8; ++j) d[j] = tof(s[j]);
        } else {
            int gg = g - 663552;
            const T* s = sinp + (size_t)gg * 8; float* d = sinf_ + (size_t)gg * 8;
#pragma unroll
            for (int j = 0; j < 8; ++j) d[j] = tof(s[j]);
        }
    } else if (b < 3264) {                // 64x64 tile transpose
        int idx = b - 2624;
        const T* src; __bf16* dst; int C;
        if (idx < 256)      { src = Wq; dst = WqT; C = 1024; }
        else if (idx < 320) { src = Wk; dst = WkT; C = 256;  idx -= 256; }
        else if (idx < 384) { src = Wv; dst = WvT; C = 256;  idx -= 320; }
        else                { src = Wp; dst = WpT; C = 1024; idx -= 384; }
        const int ctiles = C >> 6;
        const int r0 = (idx / ctiles) * 64, c0 = (idx % ctiles) * 64;
#pragma unroll
        for (int i = 0; i < 2; ++i) {
            int c = tid + i * 256, ir = c >> 3, ic = (c & 7) * 8;
            *(bf16x8*)(&tile[ir * 72 + ic]) = load8(src + (size_t)(r0 + ir) * C + c0 + ic);
        }
        __syncthreads();
#pragma unroll
        for (int i = 0; i < 2; ++i) {
            int c = tid + i * 256, orr = c >> 3, okc = (c & 7) * 8;
            bf16x8 v;
#pragma unroll
            for (int j = 0; j < 8; ++j) v[j] = tile[(okc + j) * 72 + orr];
            *(bf16x8*)(dst + (size_t)(c0 + orr) * 1024 + r0 + okc) = v;
        }
    } else {                              // gate = 2*sigmoid(x[:, :32] @ Wgate)
        int r = (b - 3264) * 256 + tid;
        float z[4] = {0.f, 0.f, 0.f, 0.f};
        for (int j = 0; j < 32; ++j) {
            float xv = tof(x[(size_t)r * 1024 + j]);
#pragma unroll
            for (int h = 0; h < 4; ++h) z[h] += xv * tof(Wg[j * 4 + h]);
        }
#pragma unroll
        for (int h = 0; h < 4; ++h) gate[r * 4 + h] = 2.f / (1.f + __expf(-z[h]));
    }
}

__global__ __launch_bounds__(256) void prep_kernel(
    const void* x, const void* ve, const void* cosp, const void* sinp,
    const void* Wq, const void* Wk, const void* Wv, const void* Wp, const void* Wg,
    __bf16* xb, __bf16* veb, float* cosf_, float* sinf_,
    __bf16* WqT, __bf16* WkT, __bf16* WvT, __bf16* WpT,
    float* gate, const int* __restrict__ flag)
{
    __shared__ __bf16 tile[64 * 72];
    if (*flag) {
        prep_body<float>((const float*)x, (const float*)ve, (const float*)cosp,
                         (const float*)sinp, (const float*)Wq, (const float*)Wk,
                         (const float*)Wv, (const float*)Wp, (const float*)Wg,
                         xb, veb, cosf_, sinf_, WqT, WkT, WvT, WpT, gate, tile);
    } else {
        prep_body<__bf16>((const __bf16*)x, (const __bf16*)ve, (const __bf16*)cosp,
                          (const __bf16*)sinp, (const __bf16*)Wq, (const __bf16*)Wk,
                          (const __bf16*)Wv, (const __bf16*)Wp, (const __bf16*)Wg,
                          xb, veb, cosf_, sinf_, WqT, WkT, WvT, WpT, gate, tile);
    }
}

// ---------------------------------------------------------------------------
// Kernel 2: QKV GEMM, 128x64 tiles (one head per block), wave = 32 rows x 64.
// V written TRANSPOSED: vT[b][kvh][d][t]. Grid: (32, 24).
// ---------------------------------------------------------------------------
__global__ __launch_bounds__(256) void qkv_kernel(
    const __bf16* __restrict__ xb,
    const __bf16* __restrict__ WqT, const __bf16* __restrict__ WkT,
    const __bf16* __restrict__ WvT, const __bf16* __restrict__ veb,
    const float* __restrict__ cosf_, const float* __restrict__ sinf_,
    const float* __restrict__ gate,
    __bf16* __restrict__ qo, __bf16* __restrict__ ko, __bf16* __restrict__ vTo)
{
    const int row0 = blockIdx.x * 128;
    const int cb = blockIdx.y;
    const __bf16* BT; int col0, h, mode;
    if (cb < 16)      { BT = WqT; col0 = cb * 64;        h = cb;      mode = 0; }
    else if (cb < 20) { BT = WkT; col0 = (cb - 16) * 64; h = cb - 16; mode = 1; }
    else              { BT = WvT; col0 = (cb - 20) * 64; h = cb - 20; mode = 2; }

    __shared__ __align__(16) __bf16 As[128 * 32];
    __shared__ __align__(16) __bf16 Bs[64 * 32];

    const int tid  = threadIdx.x;
    const int w    = tid >> 6;
    const int lane = tid & 63;
    const int quad = lane >> 4;
    const int l15  = lane & 15;
    const int wr   = w * 32;

    f32x4 acc[2][4];
#pragma unroll
    for (int mi = 0; mi < 2; ++mi)
#pragma unroll
        for (int nj = 0; nj < 4; ++nj) acc[mi][nj] = (f32x4){0.f, 0.f, 0.f, 0.f};

    for (int kk = 0; kk < 1024; kk += 32) {
#pragma unroll
        for (int i = 0; i < 2; ++i) {
            int c = i * 256 + (w << 6) + lane;
            int rr = c >> 2, kc = (c & 3) << 3;
            cp16(&As[c << 3], &xb[(size_t)(row0 + rr) * 1024 + kk + kc]);
        }
        {
            int c = (w << 6) + lane;
            int rr = c >> 2, kc = (c & 3) << 3;
            cp16(&Bs[c << 3], &BT[(size_t)(col0 + rr) * 1024 + kk + kc]);
        }
        __syncthreads();
        bf16x8 a[2], bfr[4];
#pragma unroll
        for (int mi = 0; mi < 2; ++mi) a[mi]  = *(const bf16x8*)(&As[(wr + mi * 16 + l15) * 32 + quad * 8]);
#pragma unroll
        for (int nj = 0; nj < 4; ++nj) bfr[nj] = *(const bf16x8*)(&Bs[(nj * 16 + l15) * 32 + quad * 8]);
#pragma unroll
        for (int mi = 0; mi < 2; ++mi)
#pragma unroll
            for (int nj = 0; nj < 4; ++nj)
                acc[mi][nj] = __builtin_amdgcn_mfma_f32_16x16x32_bf16(a[mi], bfr[nj], acc[mi][nj], 0, 0, 0);
        __syncthreads();
    }

    if (mode < 2) {
        __bf16* dst = (mode == 0) ? qo : ko;
        const int nh = (mode == 0) ? 16 : 4;
#pragma unroll
        for (int mi = 0; mi < 2; ++mi) {
#pragma unroll
            for (int r = 0; r < 4; ++r) {
                int row = row0 + wr + mi * 16 + quad * 4 + r;
                int b = row >> 11, t = row & 2047;
                float c0 = cosf_[t * 32 + l15];
                float c1 = cosf_[t * 32 + 16 + l15];
                float s0 = sinf_[t * 32 + l15];
                float s1 = sinf_[t * 32 + 16 + l15];
                float v0 =  c0 * acc[mi][0][r] + s0 * acc[mi][2][r];
                float v1 =  c1 * acc[mi][1][r] + s1 * acc[mi][3][r];
                float v2 = -s0 * acc[mi][0][r] + c0 * acc[mi][2][r];
                float v3 = -s1 * acc[mi][1][r] + c1 * acc[mi][3][r];
                float ss = v0 * v0 + v1 * v1 + v2 * v2 + v3 * v3;
                ss += __shfl_xor(ss, 1); ss += __shfl_xor(ss, 2);
                ss += __shfl_xor(ss, 4); ss += __shfl_xor(ss, 8);
                float sc = rsqrtf(ss * (1.f / 64.f) + 1.1920929e-7f);
                size_t base = (((size_t)b * nh + h) * 2048 + t) * 64;
                dst[base + 0 * 16 + l15] = (__bf16)(v0 * sc);
                dst[base + 1 * 16 + l15] = (__bf16)(v1 * sc);
                dst[base + 2 * 16 + l15] = (__bf16)(v2 * sc);
                dst[base + 3 * 16 + l15] = (__bf16)(v3 * sc);
            }
        }
    } else {
        // vT[(b*4+h)*64 + d][t], packed 4 consecutive t per store
#pragma unroll
        for (int mi = 0; mi < 2; ++mi) {
            int rowb = row0 + wr + mi * 16 + quad * 4;
            int b = rowb >> 11, t0 = rowb & 2047;
#pragma unroll
            for (int nj = 0; nj < 4; ++nj) {
                int d = nj * 16 + l15;
                bf16x4 pack;
#pragma unroll
                for (int r = 0; r < 4; ++r) {
                    int row = rowb + r;
                    float g = gate[row * 4 + h];
                    float val = acc[mi][nj][r] + g * tof(veb[(size_t)row * 256 + h * 64 + d]);
                    pack[r] = (__bf16)val;
                }
                size_t a = (((size_t)b * 4 + h) * 64 + d) * 2048 + t0;
                *(bf16x4*)(&vTo[a]) = pack;
            }
        }
    }
}

// ---------------------------------------------------------------------------
// Kernel 3: sliding-window causal GQA flash attention.
// Block = 128 q-rows x 1 head, wave owns 32 rows. K and V^T staged via
// async global_load_lds into XOR-swizzled unpadded 64x64 tiles (no staging
// VALU), double-buffered, ONE barrier per tile. Bounded-score softmax.
// Grid: (16, 16, 2). LDS 51.2KB -> 3 blocks/CU.
// ---------------------------------------------------------------------------
__global__ __launch_bounds__(256) void attn_kernel(
    const __bf16* __restrict__ qg, const __bf16* __restrict__ kg,
    const __bf16* __restrict__ vTg, __bf16* __restrict__ yo,
    const int* __restrict__ winp)
{
    const int q0 = blockIdx.x * 128;
    const int hh = blockIdx.y, b = blockIdx.z;
    const int kvh = hh >> 2;
    const int W = winp[0];

    const int tid  = threadIdx.x;
    const int w    = tid >> 6;
    const int lane = tid & 63;
    const int quad = lane >> 4;
    const int l15  = lane & 15;

    __shared__ __align__(16) __bf16 Ks[2][64 * 64];   // [t][d], XOR-swizzled 16B chunks
    __shared__ __align__(16) __bf16 Vt[2][64 * 64];   // [d][t], XOR-swizzled
    __shared__ __align__(16) __bf16 Ps[4][32 * 72];   // per-wave P

    bf16x8 qf[2][2];
#pragma unroll
    for (int i = 0; i < 2; ++i) {
        size_t qb = (((size_t)b * 16 + hh) * 2048 + q0 + w * 32 + i * 16 + l15) * 64;
        qf[i][0] = *(const bf16x8*)(&qg[qb + quad * 8]);
        qf[i][1] = *(const bf16x8*)(&qg[qb + 32 + quad * 8]);
    }

    f32x4 oacc[2][4];
    float lsum[2][4];
#pragma unroll
    for (int i = 0; i < 2; ++i)
#pragma unroll
        for (int n = 0; n < 4; ++n) {
            oacc[i][n] = (f32x4){0.f, 0.f, 0.f, 0.f};
            lsum[i][n] = 0.f;
        }

    const int lo = q0 - W;
    const int kt_lo = lo > 0 ? (lo >> 6) : 0;
    const int kt_hi = (q0 + 127) >> 6;
    const size_t kvbase = ((size_t)b * 4 + kvh) * 2048 * 64;   // same for kg and vTg

    // staging: 512 chunks of 16B per tile; lane chunk c -> LDS offset c*16B,
    // global chunk jj = (c&7) ^ (row&7)  [XOR swizzle for conflict-free reads]
    auto stage = [&](int buf, int k0) {
#pragma unroll
        for (int i = 0; i < 2; ++i) {
            int c = i * 256 + tid;
            int rr = c >> 3;
            int jj = (c & 7) ^ (rr & 7);
            cp16(&Ks[buf][c * 8], &kg[kvbase + (size_t)(k0 + rr) * 64 + jj * 8]);
            cp16(&Vt[buf][c * 8], &vTg[kvbase + (size_t)rr * 2048 + k0 + jj * 8]);
        }
    };

    stage(0, kt_lo * 64);
    __syncthreads();

    int cur = 0;
    for (int kt = kt_lo; kt <= kt_hi; ++kt) {
        const int k0 = kt * 64;
        const bool need_mask = (k0 + 63 > q0) || (q0 + 127 - k0 > W);
        if (kt < kt_hi) stage(cur ^ 1, k0 + 64);    // async prefetch

        // QK^T
        f32x4 sacc[2][4];
#pragma unroll
        for (int i = 0; i < 2; ++i)
#pragma unroll
            for (int n = 0; n < 4; ++n) sacc[i][n] = (f32x4){0.f, 0.f, 0.f, 0.f};
        const __bf16* Kc = &Ks[cur][0];
#pragma unroll
        for (int n = 0; n < 4; ++n) {
            int m = n * 16 + l15;
            bf16x8 b0 = *(const bf16x8*)(&Kc[m * 64 + (quad ^ (m & 7)) * 8]);
            bf16x8 b1 = *(const bf16x8*)(&Kc[m * 64 + ((4 + quad) ^ (m & 7)) * 8]);
#pragma unroll
            for (int i = 0; i < 2; ++i) {
                sacc[i][n] = __builtin_amdgcn_mfma_f32_16x16x32_bf16(qf[i][0], b0, sacc[i][n], 0, 0, 0);
                sacc[i][n] = __builtin_amdgcn_mfma_f32_16x16x32_bf16(qf[i][1], b1, sacc[i][n], 0, 0, 0);
            }
        }

        // bounded-score softmax: p = exp2(s*log2e/8 - 8*log2e)
#pragma unroll
        for (int i = 0; i < 2; ++i) {
#pragma unroll
            for (int r = 0; r < 4; ++r) {
                const int row_g = q0 + w * 32 + i * 16 + quad * 4 + r;
#pragma unroll
                for (int n = 0; n < 4; ++n) {
                    float p = exp2f(fmaf(sacc[i][n][r], 0.18033688f, -11.5415603f));
                    if (need_mask) {
                        int col_g = k0 + n * 16 + l15;
                        bool ok = (col_g <= row_g) && (row_g - col_g <= W);
                        p = ok ? p : 0.f;
                    }
                    lsum[i][r] += p;
                    Ps[w][(i * 16 + quad * 4 + r) * 72 + n * 16 + l15] = (__bf16)p;
                }
            }
        }
        asm volatile("s_waitcnt lgkmcnt(0)" ::: "memory");   // wave-local Ps ordering

        // PV
        const __bf16* Vc = &Vt[cur][0];
#pragma unroll
        for (int ks = 0; ks < 2; ++ks) {
            bf16x8 pfr0 = *(const bf16x8*)(&Ps[w][l15 * 72 + ks * 32 + quad * 8]);
            bf16x8 pfr1 = *(const bf16x8*)(&Ps[w][(16 + l15) * 72 + ks * 32 + quad * 8]);
#pragma unroll
            for (int n = 0; n < 4; ++n) {
                int m = n * 16 + l15;
                bf16x8 bv = *(const bf16x8*)(&Vc[m * 64 + ((ks * 4 + quad) ^ (m & 7)) * 8]);
                oacc[0][n] = __builtin_amdgcn_mfma_f32_16x16x32_bf16(pfr0, bv, oacc[0][n], 0, 0, 0);
                oacc[1][n] = __builtin_amdgcn_mfma_f32_16x16x32_bf16(pfr1, bv, oacc[1][n], 0, 0, 0);
            }
        }

        __syncthreads();   // drains prefetch cp16 (vmcnt) + protects buffers
        cur ^= 1;
    }

#pragma unroll
    for (int i = 0; i < 2; ++i) {
#pragma unroll
        for (int r = 0; r < 4; ++r) {
            float l = lsum[i][r];
            l += __shfl_xor(l, 1); l += __shfl_xor(l, 2);
            l += __shfl_xor(l, 4); l += __shfl_xor(l, 8);
            float inv = 1.f / l;
            int t = q0 + w * 32 + i * 16 + quad * 4 + r;
            size_t base = ((size_t)(b * 2048 + t)) * 1024 + hh * 64;
#pragma unroll
            for (int n = 0; n < 4; ++n)
                yo[base + n * 16 + l15] = (__bf16)(oacc[i][n][r] * inv);
        }
    }
}

// ---------------------------------------------------------------------------
// Kernel 4: output projection, 128x64 tiles, wave = 32x64. Grid: (32, 16).
// ---------------------------------------------------------------------------
__global__ __launch_bounds__(256) void proj_kernel(
    const __bf16* __restrict__ y, const __bf16* __restrict__ WpT,
    void* __restrict__ outp, const int* __restrict__ flag)
{
    const int isf32 = *flag;
    const int row0 = blockIdx.x * 128;
    const int col0 = blockIdx.y * 64;
    __shared__ __align__(16) __bf16 As[128 * 32];
    __shared__ __align__(16) __bf16 Bs[64 * 32];

    const int tid  = threadIdx.x;
    const int w    = tid >> 6;
    const int lane = tid & 63;
    const int quad = lane >> 4;
    const int l15  = lane & 15;
    const int wr   = w * 32;

    f32x4 acc[2][4];
#pragma unroll
    for (int mi = 0; mi < 2; ++mi)
#pragma unroll
        for (int nj = 0; nj < 4; ++nj) acc[mi][nj] = (f32x4){0.f, 0.f, 0.f, 0.f};

    for (int kk = 0; kk < 1024; kk += 32) {
#pragma unroll
        for (int i = 0; i < 2; ++i) {
            int c = i * 256 + (w << 6) + lane;
            int rr = c >> 2, kc = (c & 3) << 3;
            cp16(&As[c << 3], &y[(size_t)(row0 + rr) * 1024 + kk + kc]);
        }
        {
            int c = (w << 6) + lane;
            int rr = c >> 2, kc = (c & 3) << 3;
            cp16(&Bs[c << 3], &WpT[(size_t)(col0 + rr) * 1024 + kk + kc]);
        }
        __syncthreads();
        bf16x8 a[2], bfr[4];
#pragma unroll
        for (int mi = 0; mi < 2; ++mi) a[mi]  = *(const bf16x8*)(&As[(wr + mi * 16 + l15) * 32 + quad * 8]);
#pragma unroll
        for (int nj = 0; nj < 4; ++nj) bfr[nj] = *(const bf16x8*)(&Bs[(nj * 16 + l15) * 32 + quad * 8]);
#pragma unroll
        for (int mi = 0; mi < 2; ++mi)
#pragma unroll
            for (int nj = 0; nj < 4; ++nj)
                acc[mi][nj] = __builtin_amdgcn_mfma_f32_16x16x32_bf16(a[mi], bfr[nj], acc[mi][nj], 0, 0, 0);
        __syncthreads();
    }

#pragma unroll
    for (int mi = 0; mi < 2; ++mi)
#pragma unroll
        for (int r = 0; r < 4; ++r) {
            int row = row0 + wr + mi * 16 + quad * 4 + r;
            if (isf32) {
                float* out = (float*)outp;
#pragma unroll
                for (int nj = 0; nj < 4; ++nj)
                    out[(size_t)row * 1024 + col0 + nj * 16 + l15] = acc[mi][nj][r];
            } else {
                __bf16* out = (__bf16*)outp;
#pragma unroll
                for (int nj = 0; nj < 4; ++nj)
                    out[(size_t)row * 1024 + col0 + nj * 16 + l15] = (__bf16)acc[mi][nj][r];
            }
        }
}

extern "C" void kernel_launch(void* const* d_in, const int* in_sizes, int n_in,
                              void* d_out, int out_size, void* d_ws, size_t ws_size,
                              hipStream_t stream) {
    const int* win = (const int*)d_in[9];

    char* p = (char*)d_ws;
    int*    flag = (int*)p;                    p += 256;
    __bf16* q_ws = (__bf16*)p;                 p += (size_t)4194304 * 2;
    __bf16* k_ws = (__bf16*)p;                 p += (size_t)1048576 * 2;
    __bf16* vT_ws= (__bf16*)p;                 p += (size_t)1048576 * 2;
    __bf16* y_ws = (__bf16*)p;                 p += (size_t)4194304 * 2;
    __bf16* xb   = (__bf16*)p;                 p += (size_t)4194304 * 2;
    __bf16* veb  = (__bf16*)p;                 p += (size_t)1048576 * 2;
    __bf16* WqT  = (__bf16*)p;                 p += (size_t)1048576 * 2;
    __bf16* WkT  = (__bf16*)p;                 p += (size_t)262144 * 2;
    __bf16* WvT  = (__bf16*)p;                 p += (size_t)262144 * 2;
    __bf16* WpT  = (__bf16*)p;                 p += (size_t)1048576 * 2;
    float*  cosf_ = (float*)p;                 p += (size_t)65536 * 4;
    float*  sinf_ = (float*)p;                 p += (size_t)65536 * 4;
    float*  gate  = (float*)p;                 p += (size_t)16384 * 4;

    sniff_kernel<<<1, 64, 0, stream>>>((const unsigned short*)d_in[0], flag);

    prep_kernel<<<3280, 256, 0, stream>>>(
        d_in[0], d_in[1], d_in[2], d_in[3], d_in[4], d_in[5], d_in[6], d_in[7],
        d_in[8], xb, veb, cosf_, sinf_, WqT, WkT, WvT, WpT, gate, flag);

    qkv_kernel<<<dim3(32, 24), 256, 0, stream>>>(xb, WqT, WkT, WvT, veb,
                                                 cosf_, sinf_, gate, q_ws, k_ws, vT_ws);

    attn_kernel<<<dim3(16, 16, 2), 256, 0, stream>>>(q_ws, k_ws, vT_ws, y_ws, win);

    proj_kernel<<<dim3(32, 16), 256, 0, stream>>>(y_ws, WpT, d_out, flag);
}